// Round 1
// baseline (15457.773 us; speedup 1.0000x reference)
//
#include <hip/hip_runtime.h>
#include <cmath>

#define BATCH 2048
#define FDIM  512
#define TDIM  100
#define H1    1024
#define H2    512
#define H3    256
#define ODIM  2

// LIF update exactly mirroring the reference order:
// v_dec = v + 0.1*(i - v); i_dec = 0.8*i; z = (v_dec-1>0); v' = (1-z)*v_dec; i' = i_dec + c
__device__ __forceinline__ void lif_update(float c, float& v, float& i, float& z) {
  float vd = v + 0.1f * (i - v);
  float id = 0.8f * i;
  z = (vd - 1.0f) > 0.0f ? 1.0f : 0.0f;
  v = (z != 0.0f) ? 0.0f : vd;
  i = id + c;
}

__global__ void zero_kernel(float* __restrict__ p, int n) {
  for (int i = blockIdx.x * blockDim.x + threadIdx.x; i < n; i += gridDim.x * blockDim.x)
    p[i] = 0.0f;
}

// Layer 1 fold: input-BN scale folded into columns, BN1 scale into rows,
// constant term e1[j] = (sum_f W1[j,f]*h0[f] + b1[j] - m1[j])*sg1[j] + bb1[j]
__global__ void fold1_kernel(const float* __restrict__ W1, const float* __restrict__ b1,
                             const float* __restrict__ g1, const float* __restrict__ bb1,
                             const float* __restrict__ m1, const float* __restrict__ v1,
                             const float* __restrict__ gi, const float* __restrict__ bi,
                             const float* __restrict__ mi, const float* __restrict__ vi,
                             float* __restrict__ W1f, float* __restrict__ e1) {
  const int j = blockIdx.x;
  const int tid = threadIdx.x;
  const float sg = g1[j] / sqrtf(v1[j] + 1e-5f);
  float part = 0.0f;
  for (int f = tid; f < FDIM; f += 256) {
    float si = gi[f] / sqrtf(vi[f] + 1e-5f);
    float h0 = bi[f] - mi[f] * si;
    float w  = W1[j * FDIM + f];
    part += w * h0;
    W1f[j * FDIM + f] = w * si * sg;
  }
  #pragma unroll
  for (int m = 1; m < 64; m <<= 1) part += __shfl_xor(part, m);
  __shared__ float red[4];
  if ((tid & 63) == 0) red[tid >> 6] = part;
  __syncthreads();
  if (tid == 0) {
    float d = red[0] + red[1] + red[2] + red[3];
    e1[j] = (d + b1[j] - m1[j]) * sg + bb1[j];
  }
}

// Layers 2/3 fold: Wf[j,k] = W[j,k]*sg[j]; e[j] = (b[j]-m[j])*sg[j] + bb[j]
__global__ void foldS_kernel(const float* __restrict__ W, const float* __restrict__ b,
                             const float* __restrict__ g, const float* __restrict__ bb,
                             const float* __restrict__ m, const float* __restrict__ v,
                             float* __restrict__ Wf, float* __restrict__ e, int K) {
  const int j = blockIdx.x;
  const float sg = g[j] / sqrtf(v[j] + 1e-5f);
  for (int k = threadIdx.x; k < K; k += 256)
    Wf[j * K + k] = W[j * K + k] * sg;
  if (threadIdx.x == 0) e[j] = (b[j] - m[j]) * sg + bb[j];
}

// x (B,F,T) -> xT (T,B,F)
__global__ void transpose_kernel(const float* __restrict__ x, float* __restrict__ xT) {
  __shared__ float tile[32][33];
  const int b  = blockIdx.z;
  const int f0 = blockIdx.y * 32;
  const int t0 = blockIdx.x * 32;
  const int tx = threadIdx.x & 31, ty = threadIdx.x >> 5;
  const size_t xb = (size_t)b * FDIM * TDIM;
  #pragma unroll
  for (int r = ty; r < 32; r += 8) {
    int t = t0 + tx;
    if (t < TDIM) tile[r][tx] = x[xb + (size_t)(f0 + r) * TDIM + t];
  }
  __syncthreads();
  #pragma unroll
  for (int r = ty; r < 32; r += 8) {
    int t = t0 + r;
    if (t < TDIM) xT[(size_t)t * BATCH * FDIM + (size_t)b * FDIM + (f0 + tx)] = tile[tx][r];
  }
}

// Fused GEMM (M=2048 x N x K) + LIF epilogue.
// A: M x K via (row stride ars, col stride acs); W: N x K row-major (k-contig).
// c[b,n] = sum_k A[b,k]*W[n,k] + ebias[n]; then LIF state update, z out.
template<int TM, int TN, bool CONTIG>
__global__ __launch_bounds__(256, 2)
void gemm_lif_kernel(const float* __restrict__ A, size_t ars, size_t acs,
                     const float* __restrict__ W, const float* __restrict__ ebias,
                     float* __restrict__ vst, float* __restrict__ ist,
                     float* __restrict__ zout, int N, int K)
{
  static_assert(TN == 4, "epilogue assumes TN==4");
  constexpr int BK = 16;
  constexpr int BM = 16 * TM;
  constexpr int BN = 16 * TN;
  __shared__ float As[BK][BM];
  __shared__ float Bs[BK][BN];
  const int tid = threadIdx.x;
  const int tx = tid & 15, ty = tid >> 4;
  const int bn = blockIdx.x, bm = blockIdx.y;
  const float* Ablk = A + (size_t)bm * BM * ars;
  const float* Wblk = W + (size_t)bn * BN * (size_t)K;

  float acc[TM][TN];
  #pragma unroll
  for (int r = 0; r < TM; r++)
    #pragma unroll
    for (int c = 0; c < TN; c++) acc[r][c] = 0.0f;

  for (int k0 = 0; k0 < K; k0 += BK) {
    if (CONTIG) {
      constexpr int A4 = BM * BK / 4;
      #pragma unroll
      for (int q = 0; q < A4 / 256; q++) {
        int idx = q * 256 + tid;
        int r = idx >> 2;
        int kq = (idx & 3) << 2;
        float4 val = *reinterpret_cast<const float4*>(Ablk + (size_t)r * ars + (size_t)(k0 + kq));
        As[kq + 0][r] = val.x; As[kq + 1][r] = val.y;
        As[kq + 2][r] = val.z; As[kq + 3][r] = val.w;
      }
    } else {
      #pragma unroll
      for (int q = 0; q < BM * BK / 256; q++) {
        int idx = q * 256 + tid;
        int r = idx >> 4;
        int kk = idx & 15;
        As[kk][r] = Ablk[(size_t)r * ars + (size_t)(k0 + kk) * acs];
      }
    }
    {
      // BN*BK/4 == 256 float4s, exactly one per thread
      int n  = tid >> 2;
      int kq = (tid & 3) << 2;
      float4 val = *reinterpret_cast<const float4*>(Wblk + (size_t)n * K + (size_t)(k0 + kq));
      Bs[kq + 0][n] = val.x; Bs[kq + 1][n] = val.y;
      Bs[kq + 2][n] = val.z; Bs[kq + 3][n] = val.w;
    }
    __syncthreads();
    #pragma unroll
    for (int kk = 0; kk < BK; kk++) {
      float a[TM], bv[TN];
      const float4* ap = reinterpret_cast<const float4*>(&As[kk][ty * TM]);
      *reinterpret_cast<float4*>(&a[0]) = ap[0];
      if (TM == 8) *reinterpret_cast<float4*>(&a[4]) = ap[1];
      *reinterpret_cast<float4*>(&bv[0]) = *reinterpret_cast<const float4*>(&Bs[kk][tx * TN]);
      #pragma unroll
      for (int r = 0; r < TM; r++)
        #pragma unroll
        for (int c = 0; c < TN; c++)
          acc[r][c] = fmaf(a[r], bv[c], acc[r][c]);
    }
    __syncthreads();
  }

  const int n0 = bn * BN + tx * TN;
  const float4 ev = *reinterpret_cast<const float4*>(ebias + n0);
  #pragma unroll
  for (int r = 0; r < TM; r++) {
    const int brow = bm * BM + ty * TM + r;
    const size_t idx = (size_t)brow * N + n0;
    float c0 = acc[r][0] + ev.x;
    float c1 = acc[r][1] + ev.y;
    float c2 = acc[r][2] + ev.z;
    float c3 = acc[r][3] + ev.w;
    float4 vv = *reinterpret_cast<const float4*>(vst + idx);
    float4 ii = *reinterpret_cast<const float4*>(ist + idx);
    float4 zz;
    lif_update(c0, vv.x, ii.x, zz.x);
    lif_update(c1, vv.y, ii.y, zz.y);
    lif_update(c2, vv.z, ii.z, zz.z);
    lif_update(c3, vv.w, ii.w, zz.w);
    *reinterpret_cast<float4*>(zout + idx) = zz;
    *reinterpret_cast<float4*>(vst  + idx) = vv;
    *reinterpret_cast<float4*>(ist  + idx) = ii;
  }
}

// Output layer: co = z3 @ Wout^T + bout, LIF, acc += z*wt
__global__ void out_kernel(const float* __restrict__ z3, const float* __restrict__ Wout,
                           const float* __restrict__ bout, float* __restrict__ vo,
                           float* __restrict__ io, float* __restrict__ acc, float wt) {
  const int idx = blockIdx.x * 256 + threadIdx.x; // 0..4095
  if (idx >= BATCH * ODIM) return;
  const int b = idx >> 1, o = idx & 1;
  const float4* zr = reinterpret_cast<const float4*>(z3 + (size_t)b * H3);
  const float4* wr = reinterpret_cast<const float4*>(Wout + o * H3);
  float s = 0.0f;
  #pragma unroll 4
  for (int k = 0; k < H3 / 4; k++) {
    float4 zv = zr[k], wv = wr[k];
    s += zv.x * wv.x + zv.y * wv.y + zv.z * wv.z + zv.w * wv.w;
  }
  float cin = s + bout[o];
  float v = vo[idx], i = io[idx], z;
  lif_update(cin, v, i, z);
  vo[idx] = v; io[idx] = i;
  acc[idx] += z * wt;
}

extern "C" void kernel_launch(void* const* d_in, const int* in_sizes, int n_in,
                              void* d_out, int out_size, void* d_ws, size_t ws_size,
                              hipStream_t stream) {
  const float* x     = (const float*)d_in[0];
  const float* bni_g = (const float*)d_in[1];
  const float* bni_b = (const float*)d_in[2];
  const float* bni_m = (const float*)d_in[3];
  const float* bni_v = (const float*)d_in[4];
  const float* W1    = (const float*)d_in[5];
  const float* b1    = (const float*)d_in[6];
  const float* bn1_g = (const float*)d_in[7];
  const float* bn1_b = (const float*)d_in[8];
  const float* bn1_m = (const float*)d_in[9];
  const float* bn1_v = (const float*)d_in[10];
  const float* W2    = (const float*)d_in[11];
  const float* b2    = (const float*)d_in[12];
  const float* bn2_g = (const float*)d_in[13];
  const float* bn2_b = (const float*)d_in[14];
  const float* bn2_m = (const float*)d_in[15];
  const float* bn2_v = (const float*)d_in[16];
  const float* W3    = (const float*)d_in[17];
  const float* b3    = (const float*)d_in[18];
  const float* bn3_g = (const float*)d_in[19];
  const float* bn3_b = (const float*)d_in[20];
  const float* bn3_m = (const float*)d_in[21];
  const float* bn3_v = (const float*)d_in[22];
  const float* Wout  = (const float*)d_in[23];
  const float* bout  = (const float*)d_in[24];
  float* out = (float*)d_out;

  float* ws = (float*)d_ws;
  size_t off = 0;
  auto alloc = [&](size_t n) { float* p = ws + off; off += n; return p; };
  float* W1f = alloc((size_t)H1 * FDIM);
  float* W2f = alloc((size_t)H2 * H1);
  float* W3f = alloc((size_t)H3 * H2);
  float* e1  = alloc(H1);
  float* e2  = alloc(H2);
  float* e3  = alloc(H3);
  float* v1  = alloc((size_t)BATCH * H1);
  float* i1  = alloc((size_t)BATCH * H1);
  float* v2  = alloc((size_t)BATCH * H2);
  float* i2  = alloc((size_t)BATCH * H2);
  float* v3  = alloc((size_t)BATCH * H3);
  float* i3  = alloc((size_t)BATCH * H3);
  float* vo  = alloc((size_t)BATCH * ODIM);
  float* io  = alloc((size_t)BATCH * ODIM);
  float* z1  = alloc((size_t)BATCH * H1);
  float* z2  = alloc((size_t)BATCH * H2);
  float* z3  = alloc((size_t)BATCH * H3);
  float* xT  = ws + off;
  const size_t needed = (off + (size_t)TDIM * BATCH * FDIM) * sizeof(float);
  const bool contig = ws_size >= needed;

  // init states (contiguous block from v1 through io) and output accumulator
  const int nstate = BATCH * (2 * H1 + 2 * H2 + 2 * H3 + 2 * ODIM);
  zero_kernel<<<2048, 256, 0, stream>>>(v1, nstate);
  zero_kernel<<<16, 256, 0, stream>>>(out, BATCH * ODIM);

  // fold BN into weights
  fold1_kernel<<<H1, 256, 0, stream>>>(W1, b1, bn1_g, bn1_b, bn1_m, bn1_v,
                                       bni_g, bni_b, bni_m, bni_v, W1f, e1);
  foldS_kernel<<<H2, 256, 0, stream>>>(W2, b2, bn2_g, bn2_b, bn2_m, bn2_v, W2f, e2, H1);
  foldS_kernel<<<H3, 256, 0, stream>>>(W3, b3, bn3_g, bn3_b, bn3_m, bn3_v, W3f, e3, H2);

  if (contig)
    transpose_kernel<<<dim3(4, 16, 2048), 256, 0, stream>>>(x, xT);

  const dim3 g1(H1 / 64, BATCH / 128);
  const dim3 g2(H2 / 64, BATCH / 64);
  const dim3 g3(H3 / 64, BATCH / 64);

  for (int t = 0; t < TDIM; t++) {
    if (contig) {
      gemm_lif_kernel<8, 4, true><<<g1, 256, 0, stream>>>(
          xT + (size_t)t * BATCH * FDIM, FDIM, 1, W1f, e1, v1, i1, z1, H1, FDIM);
    } else {
      gemm_lif_kernel<8, 4, false><<<g1, 256, 0, stream>>>(
          x + t, (size_t)FDIM * TDIM, TDIM, W1f, e1, v1, i1, z1, H1, FDIM);
    }
    gemm_lif_kernel<4, 4, true><<<g2, 256, 0, stream>>>(z1, H1, 1, W2f, e2, v2, i2, z2, H2, H1);
    gemm_lif_kernel<4, 4, true><<<g3, 256, 0, stream>>>(z2, H2, 1, W3f, e3, v3, i3, z3, H3, H2);
    float wt = (float)std::pow(0.995, (double)(TDIM - 1 - t));
    out_kernel<<<BATCH * ODIM / 256, 256, 0, stream>>>(z3, Wout, bout, vo, io, out, wt);
  }
}

// Round 2
// 9130.647 us; speedup vs baseline: 1.6930x; 1.6930x over previous
//
#include <hip/hip_runtime.h>
#include <cmath>

#define BATCH 2048
#define FDIM  512
#define TDIM  100
#define H1    1024
#define H2    512
#define H3    256
#define ODIM  2

typedef __attribute__((ext_vector_type(8))) __bf16 bf16x8;
typedef __attribute__((ext_vector_type(4))) float f32x4;
typedef __attribute__((ext_vector_type(8))) unsigned short u16x8;
typedef __attribute__((ext_vector_type(4))) unsigned short u16x4;

__device__ __forceinline__ unsigned short f2bf(float f) {
  unsigned u = __builtin_bit_cast(unsigned, f);
  u = (u + 0x7fffu + ((u >> 16) & 1u)) >> 16;
  return (unsigned short)u;
}
__device__ __forceinline__ float bf2f(unsigned short h) {
  unsigned u = ((unsigned)h) << 16;
  return __builtin_bit_cast(float, u);
}
__device__ __forceinline__ void split3(float f, unsigned short& h, unsigned short& m, unsigned short& l) {
  h = f2bf(f); f -= bf2f(h);
  m = f2bf(f); f -= bf2f(m);
  l = f2bf(f);
}

// LIF update exactly mirroring the reference order
__device__ __forceinline__ void lif_update(float c, float& v, float& i, float& z) {
  float vd = v + 0.1f * (i - v);
  float id = 0.8f * i;
  z = (vd - 1.0f) > 0.0f ? 1.0f : 0.0f;
  v = (z != 0.0f) ? 0.0f : vd;
  i = id + c;
}

__global__ void zero_kernel(float* __restrict__ p, int n) {
  for (int i = blockIdx.x * blockDim.x + threadIdx.x; i < n; i += gridDim.x * blockDim.x)
    p[i] = 0.0f;
}

// x (B,F,T) -> xT (T,B,F), fp32
__global__ void transpose_kernel(const float* __restrict__ x, float* __restrict__ xT) {
  __shared__ float tile[32][33];
  const int b  = blockIdx.z;
  const int f0 = blockIdx.y * 32;
  const int t0 = blockIdx.x * 32;
  const int tx = threadIdx.x & 31, ty = threadIdx.x >> 5;
  const size_t xb = (size_t)b * FDIM * TDIM;
  #pragma unroll
  for (int r = ty; r < 32; r += 8) {
    int t = t0 + tx;
    if (t < TDIM) tile[r][tx] = x[xb + (size_t)(f0 + r) * TDIM + t];
  }
  __syncthreads();
  #pragma unroll
  for (int r = ty; r < 32; r += 8) {
    int t = t0 + r;
    if (t < TDIM) xT[(size_t)t * BATCH * FDIM + (size_t)b * FDIM + (f0 + tx)] = tile[tx][r];
  }
}

// per-step: split one t-slice of xT (fp32, BATCH x FDIM) into 3 bf16 planes
__global__ void splitx_kernel(const float* __restrict__ xt, unsigned short* __restrict__ ax) {
  const int idx = blockIdx.x * 256 + threadIdx.x;  // one float4 per thread
  const float4 v = reinterpret_cast<const float4*>(xt)[idx];
  float a[4] = {v.x, v.y, v.z, v.w};
  unsigned short h[4], m[4], l[4];
  #pragma unroll
  for (int j = 0; j < 4; j++) split3(a[j], h[j], m[j], l[j]);
  const size_t PS = (size_t)BATCH * FDIM;
  *reinterpret_cast<u16x4*>(&ax[0 * PS + (size_t)idx * 4]) = *reinterpret_cast<u16x4*>(h);
  *reinterpret_cast<u16x4*>(&ax[1 * PS + (size_t)idx * 4]) = *reinterpret_cast<u16x4*>(m);
  *reinterpret_cast<u16x4*>(&ax[2 * PS + (size_t)idx * 4]) = *reinterpret_cast<u16x4*>(l);
}

// folds producing 3-way bf16 split weight planes [3][N][K]
__global__ void fold1_mfma(const float* __restrict__ W1, const float* __restrict__ b1,
                           const float* __restrict__ g1, const float* __restrict__ bb1,
                           const float* __restrict__ m1, const float* __restrict__ v1,
                           const float* __restrict__ gi, const float* __restrict__ bi,
                           const float* __restrict__ mi, const float* __restrict__ vi,
                           unsigned short* __restrict__ W1p, float* __restrict__ e1) {
  const int j = blockIdx.x;
  const int tid = threadIdx.x;
  const float sg = g1[j] / sqrtf(v1[j] + 1e-5f);
  const size_t PS = (size_t)H1 * FDIM;
  float part = 0.0f;
  for (int f = tid; f < FDIM; f += 256) {
    float si = gi[f] / sqrtf(vi[f] + 1e-5f);
    float h0 = bi[f] - mi[f] * si;
    float w  = W1[j * FDIM + f];
    part += w * h0;
    float wf = w * si * sg;
    unsigned short h, m, l; split3(wf, h, m, l);
    W1p[0 * PS + (size_t)j * FDIM + f] = h;
    W1p[1 * PS + (size_t)j * FDIM + f] = m;
    W1p[2 * PS + (size_t)j * FDIM + f] = l;
  }
  #pragma unroll
  for (int s = 1; s < 64; s <<= 1) part += __shfl_xor(part, s);
  __shared__ float red[4];
  if ((tid & 63) == 0) red[tid >> 6] = part;
  __syncthreads();
  if (tid == 0) {
    float d = red[0] + red[1] + red[2] + red[3];
    e1[j] = (d + b1[j] - m1[j]) * sg + bb1[j];
  }
}

__global__ void foldS_mfma(const float* __restrict__ W, const float* __restrict__ b,
                           const float* __restrict__ g, const float* __restrict__ bb,
                           const float* __restrict__ m, const float* __restrict__ v,
                           unsigned short* __restrict__ Wp, float* __restrict__ e,
                           int N, int K) {
  const int j = blockIdx.x;
  const float sg = g[j] / sqrtf(v[j] + 1e-5f);
  const size_t PS = (size_t)N * K;
  for (int k = threadIdx.x; k < K; k += 256) {
    float wf = W[(size_t)j * K + k] * sg;
    unsigned short h, mm, l; split3(wf, h, mm, l);
    Wp[0 * PS + (size_t)j * K + k] = h;
    Wp[1 * PS + (size_t)j * K + k] = mm;
    Wp[2 * PS + (size_t)j * K + k] = l;
  }
  if (threadIdx.x == 0) e[j] = (b[j] - m[j]) * sg + bb[j];
}

// MFMA GEMM (M=2048 x N x K) + fused LIF epilogue.
// A: [NPL][BATCH][K] bf16 planes. Wp: [3][N][K] bf16 planes.
// c[b,n] = sum over split pairs of A_s @ W_s^T + ebias[n]; then LIF, z -> bf16.
template<int NPL, int BM, int BN>
__global__ __launch_bounds__(256, 2)
void mfma_gemm_lif(const unsigned short* __restrict__ A,
                   const unsigned short* __restrict__ Wp,
                   const float* __restrict__ ebias,
                   float* __restrict__ vst, float* __restrict__ ist,
                   unsigned short* __restrict__ zout,
                   const int N, const int K)
{
  constexpr int BK = 32, KP = 40;       // KP=40: 16B-aligned rows, 2-way-max banks
  constexpr int WTM = BM / 2, WTN = BN / 2;
  constexpr int FR = WTM / 16, FC = WTN / 16;
  __shared__ unsigned short As[NPL][BM][KP];
  __shared__ unsigned short Bs[3][BN][KP];
  const int tid = threadIdx.x;
  const int lane = tid & 63, wid = tid >> 6;
  const int wr = wid >> 1, wc = wid & 1;
  const int l16 = lane & 15, lq = lane >> 4;
  const int bnk = blockIdx.x, bmk = blockIdx.y;
  const size_t APS = (size_t)BATCH * K;
  const size_t WPS = (size_t)N * K;
  const unsigned short* Ab = A + (size_t)bmk * BM * K;
  const unsigned short* Wb = Wp + (size_t)bnk * BN * K;

  f32x4 acc[FR][FC] = {};

  for (int k0 = 0; k0 < K; k0 += BK) {
    #pragma unroll
    for (int s = 0; s < NPL; ++s)
      #pragma unroll
      for (int it = 0; it < BM / 64; ++it) {
        int idx = it * 256 + tid;
        int r = idx >> 2, kq = (idx & 3) << 3;
        *reinterpret_cast<u16x8*>(&As[s][r][kq]) =
            *reinterpret_cast<const u16x8*>(Ab + s * APS + (size_t)r * K + k0 + kq);
      }
    #pragma unroll
    for (int s = 0; s < 3; ++s)
      #pragma unroll
      for (int it = 0; it < BN / 64; ++it) {
        int idx = it * 256 + tid;
        int n = idx >> 2, kq = (idx & 3) << 3;
        *reinterpret_cast<u16x8*>(&Bs[s][n][kq]) =
            *reinterpret_cast<const u16x8*>(Wb + s * WPS + (size_t)n * K + k0 + kq);
      }
    __syncthreads();

    bf16x8 af[NPL][FR], bfr[3][FC];
    #pragma unroll
    for (int s = 0; s < NPL; ++s)
      #pragma unroll
      for (int fr = 0; fr < FR; ++fr)
        af[s][fr] = __builtin_bit_cast(bf16x8,
            *reinterpret_cast<const u16x8*>(&As[s][wr * WTM + fr * 16 + l16][lq * 8]));
    #pragma unroll
    for (int s = 0; s < 3; ++s)
      #pragma unroll
      for (int fc = 0; fc < FC; ++fc)
        bfr[s][fc] = __builtin_bit_cast(bf16x8,
            *reinterpret_cast<const u16x8*>(&Bs[s][wc * WTN + fc * 16 + l16][lq * 8]));

    constexpr int NPAIR = (NPL == 3) ? 6 : 3;
    constexpr int PA[6]  = {0, 0, 1, 0, 1, 2};
    constexpr int PB3[6] = {0, 1, 0, 2, 1, 0};
    #pragma unroll
    for (int p = 0; p < NPAIR; ++p) {
      const int sa = (NPL == 3) ? PA[p] : 0;
      const int sb = (NPL == 3) ? PB3[p] : p;
      #pragma unroll
      for (int fr = 0; fr < FR; ++fr)
        #pragma unroll
        for (int fc = 0; fc < FC; ++fc)
          acc[fr][fc] = __builtin_amdgcn_mfma_f32_16x16x32_bf16(
              af[sa][fr], bfr[sb][fc], acc[fr][fc], 0, 0, 0);
    }
    __syncthreads();
  }

  // epilogue: C/D layout col=lane&15, row=(lane>>4)*4+reg (m89-verified)
  #pragma unroll
  for (int fc = 0; fc < FC; ++fc) {
    const int n = bnk * BN + wc * WTN + fc * 16 + l16;
    const float eb = ebias[n];
    #pragma unroll
    for (int fr = 0; fr < FR; ++fr) {
      const int row0 = bmk * BM + wr * WTM + fr * 16 + lq * 4;
      #pragma unroll
      for (int r = 0; r < 4; ++r) {
        const size_t idx = (size_t)(row0 + r) * N + n;
        float c = acc[fr][fc][r] + eb;
        float v = vst[idx], ii = ist[idx], z;
        lif_update(c, v, ii, z);
        vst[idx] = v; ist[idx] = ii;
        zout[idx] = (z != 0.0f) ? (unsigned short)0x3F80 : (unsigned short)0;
      }
    }
  }
}

// Output layer: co = z3 @ Wout^T + bout, LIF, acc += z*wt   (z3 in bf16)
__global__ void out_mfma(const unsigned short* __restrict__ z3, const float* __restrict__ Wout,
                         const float* __restrict__ bout, float* __restrict__ vo,
                         float* __restrict__ io, float* __restrict__ acc, float wt) {
  const int idx = blockIdx.x * 256 + threadIdx.x;  // 0..4095
  if (idx >= BATCH * ODIM) return;
  const int b = idx >> 1, o = idx & 1;
  const unsigned short* zr = z3 + (size_t)b * H3;
  const float* wr = Wout + (size_t)o * H3;
  float s = 0.0f;
  #pragma unroll 4
  for (int k = 0; k < H3; k += 8) {
    u16x8 zv = *reinterpret_cast<const u16x8*>(zr + k);
    float4 w0 = *reinterpret_cast<const float4*>(wr + k);
    float4 w1 = *reinterpret_cast<const float4*>(wr + k + 4);
    s += bf2f(zv[0]) * w0.x + bf2f(zv[1]) * w0.y + bf2f(zv[2]) * w0.z + bf2f(zv[3]) * w0.w
       + bf2f(zv[4]) * w1.x + bf2f(zv[5]) * w1.y + bf2f(zv[6]) * w1.z + bf2f(zv[7]) * w1.w;
  }
  float cin = s + bout[o];
  float v = vo[idx], i = io[idx], z;
  lif_update(cin, v, i, z);
  vo[idx] = v; io[idx] = i;
  acc[idx] += z * wt;
}

// ---------------- fp32 fallback path (round-1 kernels) ----------------
__global__ void fold1_kernel(const float* __restrict__ W1, const float* __restrict__ b1,
                             const float* __restrict__ g1, const float* __restrict__ bb1,
                             const float* __restrict__ m1, const float* __restrict__ v1,
                             const float* __restrict__ gi, const float* __restrict__ bi,
                             const float* __restrict__ mi, const float* __restrict__ vi,
                             float* __restrict__ W1f, float* __restrict__ e1) {
  const int j = blockIdx.x;
  const int tid = threadIdx.x;
  const float sg = g1[j] / sqrtf(v1[j] + 1e-5f);
  float part = 0.0f;
  for (int f = tid; f < FDIM; f += 256) {
    float si = gi[f] / sqrtf(vi[f] + 1e-5f);
    float h0 = bi[f] - mi[f] * si;
    float w  = W1[j * FDIM + f];
    part += w * h0;
    W1f[j * FDIM + f] = w * si * sg;
  }
  #pragma unroll
  for (int m = 1; m < 64; m <<= 1) part += __shfl_xor(part, m);
  __shared__ float red[4];
  if ((tid & 63) == 0) red[tid >> 6] = part;
  __syncthreads();
  if (tid == 0) {
    float d = red[0] + red[1] + red[2] + red[3];
    e1[j] = (d + b1[j] - m1[j]) * sg + bb1[j];
  }
}

__global__ void foldS_kernel(const float* __restrict__ W, const float* __restrict__ b,
                             const float* __restrict__ g, const float* __restrict__ bb,
                             const float* __restrict__ m, const float* __restrict__ v,
                             float* __restrict__ Wf, float* __restrict__ e, int K) {
  const int j = blockIdx.x;
  const float sg = g[j] / sqrtf(v[j] + 1e-5f);
  for (int k = threadIdx.x; k < K; k += 256)
    Wf[j * K + k] = W[j * K + k] * sg;
  if (threadIdx.x == 0) e[j] = (b[j] - m[j]) * sg + bb[j];
}

template<int TM, int TN, bool CONTIG>
__global__ __launch_bounds__(256, 2)
void gemm_lif_kernel(const float* __restrict__ A, size_t ars, size_t acs,
                     const float* __restrict__ W, const float* __restrict__ ebias,
                     float* __restrict__ vst, float* __restrict__ ist,
                     float* __restrict__ zout, int N, int K)
{
  constexpr int BK = 16;
  constexpr int BM = 16 * TM;
  constexpr int BN = 16 * TN;
  __shared__ float As[BK][BM];
  __shared__ float Bs[BK][BN];
  const int tid = threadIdx.x;
  const int tx = tid & 15, ty = tid >> 4;
  const int bn = blockIdx.x, bm = blockIdx.y;
  const float* Ablk = A + (size_t)bm * BM * ars;
  const float* Wblk = W + (size_t)bn * BN * (size_t)K;

  float acc[TM][TN];
  #pragma unroll
  for (int r = 0; r < TM; r++)
    #pragma unroll
    for (int c = 0; c < TN; c++) acc[r][c] = 0.0f;

  for (int k0 = 0; k0 < K; k0 += BK) {
    if (CONTIG) {
      constexpr int A4 = BM * BK / 4;
      #pragma unroll
      for (int q = 0; q < A4 / 256; q++) {
        int idx = q * 256 + tid;
        int r = idx >> 2;
        int kq = (idx & 3) << 2;
        float4 val = *reinterpret_cast<const float4*>(Ablk + (size_t)r * ars + (size_t)(k0 + kq));
        As[kq + 0][r] = val.x; As[kq + 1][r] = val.y;
        As[kq + 2][r] = val.z; As[kq + 3][r] = val.w;
      }
    } else {
      #pragma unroll
      for (int q = 0; q < BM * BK / 256; q++) {
        int idx = q * 256 + tid;
        int r = idx >> 4;
        int kk = idx & 15;
        As[kk][r] = Ablk[(size_t)r * ars + (size_t)(k0 + kk) * acs];
      }
    }
    {
      int n  = tid >> 2;
      int kq = (tid & 3) << 2;
      float4 val = *reinterpret_cast<const float4*>(Wblk + (size_t)n * K + (size_t)(k0 + kq));
      Bs[kq + 0][n] = val.x; Bs[kq + 1][n] = val.y;
      Bs[kq + 2][n] = val.z; Bs[kq + 3][n] = val.w;
    }
    __syncthreads();
    #pragma unroll
    for (int kk = 0; kk < BK; kk++) {
      float a[TM], bv[TN];
      const float4* ap = reinterpret_cast<const float4*>(&As[kk][ty * TM]);
      *reinterpret_cast<float4*>(&a[0]) = ap[0];
      if (TM == 8) *reinterpret_cast<float4*>(&a[4]) = ap[1];
      *reinterpret_cast<float4*>(&bv[0]) = *reinterpret_cast<const float4*>(&Bs[kk][tx * TN]);
      #pragma unroll
      for (int r = 0; r < TM; r++)
        #pragma unroll
        for (int c = 0; c < TN; c++)
          acc[r][c] = fmaf(a[r], bv[c], acc[r][c]);
    }
    __syncthreads();
  }

  const int n0 = bn * BN + tx * TN;
  const float4 ev = *reinterpret_cast<const float4*>(ebias + n0);
  #pragma unroll
  for (int r = 0; r < TM; r++) {
    const int brow = bm * BM + ty * TM + r;
    const size_t idx = (size_t)brow * N + n0;
    float c0 = acc[r][0] + ev.x;
    float c1 = acc[r][1] + ev.y;
    float c2 = acc[r][2] + ev.z;
    float c3 = acc[r][3] + ev.w;
    float4 vv = *reinterpret_cast<const float4*>(vst + idx);
    float4 ii = *reinterpret_cast<const float4*>(ist + idx);
    float4 zz;
    lif_update(c0, vv.x, ii.x, zz.x);
    lif_update(c1, vv.y, ii.y, zz.y);
    lif_update(c2, vv.z, ii.z, zz.z);
    lif_update(c3, vv.w, ii.w, zz.w);
    *reinterpret_cast<float4*>(zout + idx) = zz;
    *reinterpret_cast<float4*>(vst  + idx) = vv;
    *reinterpret_cast<float4*>(ist  + idx) = ii;
  }
}

__global__ void out_kernel(const float* __restrict__ z3, const float* __restrict__ Wout,
                           const float* __restrict__ bout, float* __restrict__ vo,
                           float* __restrict__ io, float* __restrict__ acc, float wt) {
  const int idx = blockIdx.x * 256 + threadIdx.x;
  if (idx >= BATCH * ODIM) return;
  const int b = idx >> 1, o = idx & 1;
  const float4* zr = reinterpret_cast<const float4*>(z3 + (size_t)b * H3);
  const float4* wr = reinterpret_cast<const float4*>(Wout + o * H3);
  float s = 0.0f;
  #pragma unroll 4
  for (int k = 0; k < H3 / 4; k++) {
    float4 zv = zr[k], wv = wr[k];
    s += zv.x * wv.x + zv.y * wv.y + zv.z * wv.z + zv.w * wv.w;
  }
  float cin = s + bout[o];
  float v = vo[idx], i = io[idx], z;
  lif_update(cin, v, i, z);
  vo[idx] = v; io[idx] = i;
  acc[idx] += z * wt;
}

extern "C" void kernel_launch(void* const* d_in, const int* in_sizes, int n_in,
                              void* d_out, int out_size, void* d_ws, size_t ws_size,
                              hipStream_t stream) {
  const float* x     = (const float*)d_in[0];
  const float* bni_g = (const float*)d_in[1];
  const float* bni_b = (const float*)d_in[2];
  const float* bni_m = (const float*)d_in[3];
  const float* bni_v = (const float*)d_in[4];
  const float* W1    = (const float*)d_in[5];
  const float* b1    = (const float*)d_in[6];
  const float* bn1_g = (const float*)d_in[7];
  const float* bn1_b = (const float*)d_in[8];
  const float* bn1_m = (const float*)d_in[9];
  const float* bn1_v = (const float*)d_in[10];
  const float* W2    = (const float*)d_in[11];
  const float* b2    = (const float*)d_in[12];
  const float* bn2_g = (const float*)d_in[13];
  const float* bn2_b = (const float*)d_in[14];
  const float* bn2_m = (const float*)d_in[15];
  const float* bn2_v = (const float*)d_in[16];
  const float* W3    = (const float*)d_in[17];
  const float* b3    = (const float*)d_in[18];
  const float* bn3_g = (const float*)d_in[19];
  const float* bn3_b = (const float*)d_in[20];
  const float* bn3_m = (const float*)d_in[21];
  const float* bn3_v = (const float*)d_in[22];
  const float* Wout  = (const float*)d_in[23];
  const float* bout  = (const float*)d_in[24];
  float* out = (float*)d_out;

  float* ws = (float*)d_ws;
  size_t off = 0;
  auto alloc = [&](size_t n) { float* p = ws + off; off += n; return p; };

  // ---- MFMA path layout ----
  float* e1 = alloc(H1);
  float* e2 = alloc(H2);
  float* e3 = alloc(H3);
  float* v1 = alloc((size_t)BATCH * H1);
  float* i1 = alloc((size_t)BATCH * H1);
  float* v2 = alloc((size_t)BATCH * H2);
  float* i2 = alloc((size_t)BATCH * H2);
  float* v3 = alloc((size_t)BATCH * H3);
  float* i3 = alloc((size_t)BATCH * H3);
  float* vo = alloc((size_t)BATCH * ODIM);
  float* io = alloc((size_t)BATCH * ODIM);
  float* xT = alloc((size_t)TDIM * BATCH * FDIM);
  unsigned short* us = (unsigned short*)(ws + off);
  size_t uoff = 0;
  auto ualloc = [&](size_t n) { unsigned short* p = us + uoff; uoff += n; return p; };
  unsigned short* W1p = ualloc((size_t)3 * H1 * FDIM);
  unsigned short* W2p = ualloc((size_t)3 * H2 * H1);
  unsigned short* W3p = ualloc((size_t)3 * H3 * H2);
  unsigned short* z1u = ualloc((size_t)BATCH * H1);
  unsigned short* z2u = ualloc((size_t)BATCH * H2);
  unsigned short* z3u = ualloc((size_t)BATCH * H3);
  unsigned short* Axp = ualloc((size_t)3 * BATCH * FDIM);
  const size_t mfma_needed = off * sizeof(float) + uoff * sizeof(unsigned short);

  const int nstate = BATCH * (2 * H1 + 2 * H2 + 2 * H3 + 2 * ODIM);

  if (ws_size >= mfma_needed) {
    zero_kernel<<<2048, 256, 0, stream>>>(v1, nstate);
    zero_kernel<<<16, 256, 0, stream>>>(out, BATCH * ODIM);

    fold1_mfma<<<H1, 256, 0, stream>>>(W1, b1, bn1_g, bn1_b, bn1_m, bn1_v,
                                       bni_g, bni_b, bni_m, bni_v, W1p, e1);
    foldS_mfma<<<H2, 256, 0, stream>>>(W2, b2, bn2_g, bn2_b, bn2_m, bn2_v, W2p, e2, H2, H1);
    foldS_mfma<<<H3, 256, 0, stream>>>(W3, b3, bn3_g, bn3_b, bn3_m, bn3_v, W3p, e3, H3, H2);
    transpose_kernel<<<dim3(4, 16, 2048), 256, 0, stream>>>(x, xT);

    const dim3 g1(H1 / 64, BATCH / 128);   // (16,16)
    const dim3 g2(H2 / 64, BATCH / 64);    // (8,32)
    const dim3 g3(H3 / 64, BATCH / 64);    // (4,32)

    for (int t = 0; t < TDIM; t++) {
      splitx_kernel<<<BATCH * FDIM / 1024, 256, 0, stream>>>(xT + (size_t)t * BATCH * FDIM, Axp);
      mfma_gemm_lif<3, 128, 64><<<g1, 256, 0, stream>>>(Axp, W1p, e1, v1, i1, z1u, H1, FDIM);
      mfma_gemm_lif<1, 64, 64><<<g2, 256, 0, stream>>>(z1u, W2p, e2, v2, i2, z2u, H2, H1);
      mfma_gemm_lif<1, 64, 64><<<g3, 256, 0, stream>>>(z2u, W3p, e3, v3, i3, z3u, H3, H2);
      float wt = (float)std::pow(0.995, (double)(TDIM - 1 - t));
      out_mfma<<<BATCH * ODIM / 256, 256, 0, stream>>>(z3u, Wout, bout, vo, io, out, wt);
    }
    return;
  }

  // ---- fp32 fallback (strided GEMM1, no xT) ----
  off = 0;
  float* W1f = alloc((size_t)H1 * FDIM);
  float* W2f = alloc((size_t)H2 * H1);
  float* W3f = alloc((size_t)H3 * H2);
  float* fe1 = alloc(H1);
  float* fe2 = alloc(H2);
  float* fe3 = alloc(H3);
  float* fv1 = alloc((size_t)BATCH * H1);
  float* fi1 = alloc((size_t)BATCH * H1);
  float* fv2 = alloc((size_t)BATCH * H2);
  float* fi2 = alloc((size_t)BATCH * H2);
  float* fv3 = alloc((size_t)BATCH * H3);
  float* fi3 = alloc((size_t)BATCH * H3);
  float* fvo = alloc((size_t)BATCH * ODIM);
  float* fio = alloc((size_t)BATCH * ODIM);
  float* z1  = alloc((size_t)BATCH * H1);
  float* z2  = alloc((size_t)BATCH * H2);
  float* z3  = alloc((size_t)BATCH * H3);

  zero_kernel<<<2048, 256, 0, stream>>>(fv1, nstate);
  zero_kernel<<<16, 256, 0, stream>>>(out, BATCH * ODIM);

  fold1_kernel<<<H1, 256, 0, stream>>>(W1, b1, bn1_g, bn1_b, bn1_m, bn1_v,
                                       bni_g, bni_b, bni_m, bni_v, W1f, fe1);
  foldS_kernel<<<H2, 256, 0, stream>>>(W2, b2, bn2_g, bn2_b, bn2_m, bn2_v, W2f, fe2, H1);
  foldS_kernel<<<H3, 256, 0, stream>>>(W3, b3, bn3_g, bn3_b, bn3_m, bn3_v, W3f, fe3, H2);

  const dim3 fg1(H1 / 64, BATCH / 128);
  const dim3 fg2(H2 / 64, BATCH / 64);
  const dim3 fg3(H3 / 64, BATCH / 64);

  for (int t = 0; t < TDIM; t++) {
    gemm_lif_kernel<8, 4, false><<<fg1, 256, 0, stream>>>(
        x + t, (size_t)FDIM * TDIM, TDIM, W1f, fe1, fv1, fi1, z1, H1, FDIM);
    gemm_lif_kernel<4, 4, true><<<fg2, 256, 0, stream>>>(z1, H1, 1, W2f, fe2, fv2, fi2, z2, H2, H1);
    gemm_lif_kernel<4, 4, true><<<fg3, 256, 0, stream>>>(z2, H2, 1, W3f, fe3, fv3, fi3, z3, H3, H2);
    float wt = (float)std::pow(0.995, (double)(TDIM - 1 - t));
    out_kernel<<<BATCH * ODIM / 256, 256, 0, stream>>>(z3, Wout, bout, fvo, fio, out, wt);
  }
}

// Round 3
// 6066.969 us; speedup vs baseline: 2.5479x; 1.5050x over previous
//
#include <hip/hip_runtime.h>
#include <cmath>

#define BATCH 2048
#define FDIM  512
#define TDIM  100
#define H1    1024
#define H2    512
#define H3    256
#define ODIM  2

typedef __attribute__((ext_vector_type(8))) __bf16 bf16x8;
typedef __attribute__((ext_vector_type(4))) float f32x4;
typedef __attribute__((ext_vector_type(8))) unsigned short u16x8;
typedef __attribute__((ext_vector_type(4))) unsigned short u16x4;

__device__ __forceinline__ unsigned short f2bf(float f) {
  unsigned u = __builtin_bit_cast(unsigned, f);
  u = (u + 0x7fffu + ((u >> 16) & 1u)) >> 16;
  return (unsigned short)u;
}
__device__ __forceinline__ float bf2f(unsigned short h) {
  unsigned u = ((unsigned)h) << 16;
  return __builtin_bit_cast(float, u);
}
__device__ __forceinline__ void split3(float f, unsigned short& h, unsigned short& m, unsigned short& l) {
  h = f2bf(f); f -= bf2f(h);
  m = f2bf(f); f -= bf2f(m);
  l = f2bf(f);
}

__device__ __forceinline__ void gl16(const void* g, void* l) {
  __builtin_amdgcn_global_load_lds(
      (const __attribute__((address_space(1))) unsigned int*)g,
      (__attribute__((address_space(3))) unsigned int*)l, 16, 0, 0);
}

// LIF update exactly mirroring the reference order
__device__ __forceinline__ void lif_update(float c, float& v, float& i, float& z) {
  float vd = v + 0.1f * (i - v);
  float id = 0.8f * i;
  z = (vd - 1.0f) > 0.0f ? 1.0f : 0.0f;
  v = (z != 0.0f) ? 0.0f : vd;
  i = id + c;
}

__global__ void zero_kernel(float* __restrict__ p, int n) {
  for (int i = blockIdx.x * blockDim.x + threadIdx.x; i < n; i += gridDim.x * blockDim.x)
    p[i] = 0.0f;
}

// x (B,F,T) -> xT (T,B,F), fp32
__global__ void transpose_kernel(const float* __restrict__ x, float* __restrict__ xT) {
  __shared__ float tile[32][33];
  const int b  = blockIdx.z;
  const int f0 = blockIdx.y * 32;
  const int t0 = blockIdx.x * 32;
  const int tx = threadIdx.x & 31, ty = threadIdx.x >> 5;
  const size_t xb = (size_t)b * FDIM * TDIM;
  #pragma unroll
  for (int r = ty; r < 32; r += 8) {
    int t = t0 + tx;
    if (t < TDIM) tile[r][tx] = x[xb + (size_t)(f0 + r) * TDIM + t];
  }
  __syncthreads();
  #pragma unroll
  for (int r = ty; r < 32; r += 8) {
    int t = t0 + r;
    if (t < TDIM) xT[(size_t)t * BATCH * FDIM + (size_t)b * FDIM + (f0 + tx)] = tile[tx][r];
  }
}

__device__ __forceinline__ void split_chunk(const float* __restrict__ xt,
                                            unsigned short* __restrict__ ax, int idx) {
  const float4 v = reinterpret_cast<const float4*>(xt)[idx];
  float a[4] = {v.x, v.y, v.z, v.w};
  unsigned short h[4], m[4], l[4];
  #pragma unroll
  for (int j = 0; j < 4; j++) split3(a[j], h[j], m[j], l[j]);
  const size_t PS = (size_t)BATCH * FDIM;
  *reinterpret_cast<u16x4*>(&ax[0 * PS + (size_t)idx * 4]) = *reinterpret_cast<u16x4*>(h);
  *reinterpret_cast<u16x4*>(&ax[1 * PS + (size_t)idx * 4]) = *reinterpret_cast<u16x4*>(m);
  *reinterpret_cast<u16x4*>(&ax[2 * PS + (size_t)idx * 4]) = *reinterpret_cast<u16x4*>(l);
}

__global__ void splitx_kernel(const float* __restrict__ xt, unsigned short* __restrict__ ax) {
  split_chunk(xt, ax, blockIdx.x * 256 + threadIdx.x);
}

// fused: out-layer LIF for step t  +  split of x slice for step t+1
__global__ void tail_kernel(const unsigned short* __restrict__ z3, const float* __restrict__ Wout,
                            const float* __restrict__ bout, float* __restrict__ vo,
                            float* __restrict__ io, float* __restrict__ acc, float wt,
                            const float* __restrict__ xt_next, unsigned short* __restrict__ ax,
                            int do_split) {
  const int bid = blockIdx.x;
  if (bid < 16) {
    const int idx = bid * 256 + threadIdx.x;  // 0..4095
    const int b = idx >> 1, o = idx & 1;
    const unsigned short* zr = z3 + (size_t)b * H3;
    const float* wr = Wout + (size_t)o * H3;
    float s = 0.0f;
    #pragma unroll 4
    for (int k = 0; k < H3; k += 8) {
      u16x8 zv = *reinterpret_cast<const u16x8*>(zr + k);
      float4 w0 = *reinterpret_cast<const float4*>(wr + k);
      float4 w1 = *reinterpret_cast<const float4*>(wr + k + 4);
      s += bf2f(zv[0]) * w0.x + bf2f(zv[1]) * w0.y + bf2f(zv[2]) * w0.z + bf2f(zv[3]) * w0.w
         + bf2f(zv[4]) * w1.x + bf2f(zv[5]) * w1.y + bf2f(zv[6]) * w1.z + bf2f(zv[7]) * w1.w;
    }
    float cin = s + bout[o];
    float v = vo[idx], i = io[idx], z;
    lif_update(cin, v, i, z);
    vo[idx] = v; io[idx] = i;
    acc[idx] += z * wt;
  } else if (do_split) {
    split_chunk(xt_next, ax, (bid - 16) * 256 + threadIdx.x);
  }
}

// folds producing 3-way bf16 split weight planes [3][N][K]
__global__ void fold1_mfma(const float* __restrict__ W1, const float* __restrict__ b1,
                           const float* __restrict__ g1, const float* __restrict__ bb1,
                           const float* __restrict__ m1, const float* __restrict__ v1,
                           const float* __restrict__ gi, const float* __restrict__ bi,
                           const float* __restrict__ mi, const float* __restrict__ vi,
                           unsigned short* __restrict__ W1p, float* __restrict__ e1) {
  const int j = blockIdx.x;
  const int tid = threadIdx.x;
  const float sg = g1[j] / sqrtf(v1[j] + 1e-5f);
  const size_t PS = (size_t)H1 * FDIM;
  float part = 0.0f;
  for (int f = tid; f < FDIM; f += 256) {
    float si = gi[f] / sqrtf(vi[f] + 1e-5f);
    float h0 = bi[f] - mi[f] * si;
    float w  = W1[j * FDIM + f];
    part += w * h0;
    float wf = w * si * sg;
    unsigned short h, m, l; split3(wf, h, m, l);
    W1p[0 * PS + (size_t)j * FDIM + f] = h;
    W1p[1 * PS + (size_t)j * FDIM + f] = m;
    W1p[2 * PS + (size_t)j * FDIM + f] = l;
  }
  #pragma unroll
  for (int s = 1; s < 64; s <<= 1) part += __shfl_xor(part, s);
  __shared__ float red[4];
  if ((tid & 63) == 0) red[tid >> 6] = part;
  __syncthreads();
  if (tid == 0) {
    float d = red[0] + red[1] + red[2] + red[3];
    e1[j] = (d + b1[j] - m1[j]) * sg + bb1[j];
  }
}

__global__ void foldS_mfma(const float* __restrict__ W, const float* __restrict__ b,
                           const float* __restrict__ g, const float* __restrict__ bb,
                           const float* __restrict__ m, const float* __restrict__ v,
                           unsigned short* __restrict__ Wp, float* __restrict__ e,
                           int N, int K) {
  const int j = blockIdx.x;
  const float sg = g[j] / sqrtf(v[j] + 1e-5f);
  const size_t PS = (size_t)N * K;
  for (int k = threadIdx.x; k < K; k += 256) {
    float wf = W[(size_t)j * K + k] * sg;
    unsigned short h, mm, l; split3(wf, h, mm, l);
    Wp[0 * PS + (size_t)j * K + k] = h;
    Wp[1 * PS + (size_t)j * K + k] = mm;
    Wp[2 * PS + (size_t)j * K + k] = l;
  }
  if (threadIdx.x == 0) e[j] = (b[j] - m[j]) * sg + bb[j];
}

// MFMA GEMM (M=2048 x N x K) + fused LIF epilogue.
// A: [NPL][BATCH][K] bf16 planes. Wp: [3][N][K] bf16 planes.
// Staging: global_load_lds width-16, linear LDS rows of BK=64 bf16 (128B),
// XOR swizzle slot^=(row&7) applied at the global SOURCE and at ds_read.
template<int NPL, int BM, int BN>
__global__ __launch_bounds__(256, 2)
void mfma_gemm_lif(const unsigned short* __restrict__ A,
                   const unsigned short* __restrict__ Wp,
                   const float* __restrict__ ebias,
                   float* __restrict__ vst, float* __restrict__ ist,
                   unsigned short* __restrict__ zout,
                   const int N, const int K)
{
  constexpr int BK = 64;
  constexpr int WTM = BM / 2, WTN = BN / 2;   // 2x2 wave grid
  constexpr int FR = WTM / 16, FC = WTN / 16;
  constexpr int RA = BM / 8;                  // gload instrs per A plane
  constexpr int RB = BN / 8;
  __shared__ unsigned short As[NPL][BM][BK];
  __shared__ unsigned short Bs[3][BN][BK];
  const int tid = threadIdx.x;
  const int lane = tid & 63, wid = tid >> 6;
  const int wr = wid >> 1, wc = wid & 1;
  const int l16 = lane & 15, lq = lane >> 4;
  const int bnk = blockIdx.x, bmk = blockIdx.y;
  const size_t APS = (size_t)BATCH * K;
  const size_t WPS = (size_t)N * K;

  f32x4 acc[FR][FC] = {};

  const int lrow8 = lane >> 3;          // 0..7: row within 8-row group
  const int lslot = lane & 7;           // linear 16B slot

  auto stage = [&](int it) {
    const int k0 = it * BK;
    #pragma unroll
    for (int q = 0; q < NPL * RA / 4; ++q) {
      int i = q * 4 + wid;
      int s = i / RA, r0 = (i % RA) * 8;
      int row = r0 + lrow8;
      int srcslot = lslot ^ (row & 7);
      const unsigned short* g = A + (size_t)s * APS +
          (size_t)(bmk * BM + row) * K + (size_t)k0 + srcslot * 8;
      gl16(g, &As[s][r0][0]);
    }
    #pragma unroll
    for (int q = 0; q < 3 * RB / 4; ++q) {
      int i = q * 4 + wid;
      int s = i / RB, r0 = (i % RB) * 8;
      int row = r0 + lrow8;
      int srcslot = lslot ^ (row & 7);
      const unsigned short* g = Wp + (size_t)s * WPS +
          (size_t)(bnk * BN + row) * K + (size_t)k0 + srcslot * 8;
      gl16(g, &Bs[s][r0][0]);
    }
  };

  stage(0);
  __syncthreads();

  const int NK = K / BK;
  for (int it = 0; it < NK; ++it) {
    bf16x8 af[2][NPL][FR], bfr[2][3][FC];
    #pragma unroll
    for (int kh = 0; kh < 2; ++kh) {
      #pragma unroll
      for (int s = 0; s < NPL; ++s)
        #pragma unroll
        for (int fr = 0; fr < FR; ++fr) {
          int row = wr * WTM + fr * 16 + l16;
          int slot = ((kh << 2) | lq) ^ (row & 7);
          af[kh][s][fr] = __builtin_bit_cast(bf16x8,
              *reinterpret_cast<const u16x8*>(&As[s][row][slot * 8]));
        }
      #pragma unroll
      for (int s = 0; s < 3; ++s)
        #pragma unroll
        for (int fc = 0; fc < FC; ++fc) {
          int row = wc * WTN + fc * 16 + l16;
          int slot = ((kh << 2) | lq) ^ (row & 7);
          bfr[kh][s][fc] = __builtin_bit_cast(bf16x8,
              *reinterpret_cast<const u16x8*>(&Bs[s][row][slot * 8]));
        }
    }
    __syncthreads();                    // all waves done reading this tile
    if (it + 1 < NK) stage(it + 1);     // async writes fly under the MFMAs

    constexpr int NPAIR = (NPL == 3) ? 6 : 3;
    constexpr int PA[6]  = {0, 0, 1, 0, 1, 2};
    constexpr int PB3[6] = {0, 1, 0, 2, 1, 0};
    #pragma unroll
    for (int kh = 0; kh < 2; ++kh)
      #pragma unroll
      for (int p = 0; p < NPAIR; ++p) {
        const int sa = (NPL == 3) ? PA[p] : 0;
        const int sb = (NPL == 3) ? PB3[p] : p;
        #pragma unroll
        for (int fr = 0; fr < FR; ++fr)
          #pragma unroll
          for (int fc = 0; fc < FC; ++fc)
            acc[fr][fc] = __builtin_amdgcn_mfma_f32_16x16x32_bf16(
                af[kh][sa][fr], bfr[kh][sb][fc], acc[fr][fc], 0, 0, 0);
      }
    __syncthreads();                    // drains vmcnt -> staged tile visible
  }

  // epilogue: C/D layout col=lane&15, row=(lane>>4)*4+reg (m89-verified)
  #pragma unroll
  for (int fc = 0; fc < FC; ++fc) {
    const int n = bnk * BN + wc * WTN + fc * 16 + l16;
    const float eb = ebias[n];
    #pragma unroll
    for (int fr = 0; fr < FR; ++fr) {
      const int row0 = bmk * BM + wr * WTM + fr * 16 + lq * 4;
      #pragma unroll
      for (int r = 0; r < 4; ++r) {
        const size_t idx = (size_t)(row0 + r) * N + n;
        float c = acc[fr][fc][r] + eb;
        float v = vst[idx], ii = ist[idx], z;
        lif_update(c, v, ii, z);
        vst[idx] = v; ist[idx] = ii;
        zout[idx] = (z != 0.0f) ? (unsigned short)0x3F80 : (unsigned short)0;
      }
    }
  }
}

// ---------------- fp32 fallback path (round-1 kernels) ----------------
__global__ void fold1_kernel(const float* __restrict__ W1, const float* __restrict__ b1,
                             const float* __restrict__ g1, const float* __restrict__ bb1,
                             const float* __restrict__ m1, const float* __restrict__ v1,
                             const float* __restrict__ gi, const float* __restrict__ bi,
                             const float* __restrict__ mi, const float* __restrict__ vi,
                             float* __restrict__ W1f, float* __restrict__ e1) {
  const int j = blockIdx.x;
  const int tid = threadIdx.x;
  const float sg = g1[j] / sqrtf(v1[j] + 1e-5f);
  float part = 0.0f;
  for (int f = tid; f < FDIM; f += 256) {
    float si = gi[f] / sqrtf(vi[f] + 1e-5f);
    float h0 = bi[f] - mi[f] * si;
    float w  = W1[j * FDIM + f];
    part += w * h0;
    W1f[j * FDIM + f] = w * si * sg;
  }
  #pragma unroll
  for (int m = 1; m < 64; m <<= 1) part += __shfl_xor(part, m);
  __shared__ float red[4];
  if ((tid & 63) == 0) red[tid >> 6] = part;
  __syncthreads();
  if (tid == 0) {
    float d = red[0] + red[1] + red[2] + red[3];
    e1[j] = (d + b1[j] - m1[j]) * sg + bb1[j];
  }
}

__global__ void foldS_kernel(const float* __restrict__ W, const float* __restrict__ b,
                             const float* __restrict__ g, const float* __restrict__ bb,
                             const float* __restrict__ m, const float* __restrict__ v,
                             float* __restrict__ Wf, float* __restrict__ e, int K) {
  const int j = blockIdx.x;
  const float sg = g[j] / sqrtf(v[j] + 1e-5f);
  for (int k = threadIdx.x; k < K; k += 256)
    Wf[j * K + k] = W[j * K + k] * sg;
  if (threadIdx.x == 0) e[j] = (b[j] - m[j]) * sg + bb[j];
}

template<int TM, int TN, bool CONTIG>
__global__ __launch_bounds__(256, 2)
void gemm_lif_kernel(const float* __restrict__ A, size_t ars, size_t acs,
                     const float* __restrict__ W, const float* __restrict__ ebias,
                     float* __restrict__ vst, float* __restrict__ ist,
                     float* __restrict__ zout, int N, int K)
{
  constexpr int BK = 16;
  constexpr int BM = 16 * TM;
  constexpr int BN = 16 * TN;
  __shared__ float As[BK][BM];
  __shared__ float Bs[BK][BN];
  const int tid = threadIdx.x;
  const int tx = tid & 15, ty = tid >> 4;
  const int bn = blockIdx.x, bm = blockIdx.y;
  const float* Ablk = A + (size_t)bm * BM * ars;
  const float* Wblk = W + (size_t)bn * BN * (size_t)K;

  float acc[TM][TN];
  #pragma unroll
  for (int r = 0; r < TM; r++)
    #pragma unroll
    for (int c = 0; c < TN; c++) acc[r][c] = 0.0f;

  for (int k0 = 0; k0 < K; k0 += BK) {
    if (CONTIG) {
      constexpr int A4 = BM * BK / 4;
      #pragma unroll
      for (int q = 0; q < A4 / 256; q++) {
        int idx = q * 256 + tid;
        int r = idx >> 2;
        int kq = (idx & 3) << 2;
        float4 val = *reinterpret_cast<const float4*>(Ablk + (size_t)r * ars + (size_t)(k0 + kq));
        As[kq + 0][r] = val.x; As[kq + 1][r] = val.y;
        As[kq + 2][r] = val.z; As[kq + 3][r] = val.w;
      }
    } else {
      #pragma unroll
      for (int q = 0; q < BM * BK / 256; q++) {
        int idx = q * 256 + tid;
        int r = idx >> 4;
        int kk = idx & 15;
        As[kk][r] = Ablk[(size_t)r * ars + (size_t)(k0 + kk) * acs];
      }
    }
    {
      int n  = tid >> 2;
      int kq = (tid & 3) << 2;
      float4 val = *reinterpret_cast<const float4*>(Wblk + (size_t)n * K + (size_t)(k0 + kq));
      Bs[kq + 0][n] = val.x; Bs[kq + 1][n] = val.y;
      Bs[kq + 2][n] = val.z; Bs[kq + 3][n] = val.w;
    }
    __syncthreads();
    #pragma unroll
    for (int kk = 0; kk < BK; kk++) {
      float a[TM], bv[TN];
      const float4* ap = reinterpret_cast<const float4*>(&As[kk][ty * TM]);
      *reinterpret_cast<float4*>(&a[0]) = ap[0];
      if (TM == 8) *reinterpret_cast<float4*>(&a[4]) = ap[1];
      *reinterpret_cast<float4*>(&bv[0]) = *reinterpret_cast<const float4*>(&Bs[kk][tx * TN]);
      #pragma unroll
      for (int r = 0; r < TM; r++)
        #pragma unroll
        for (int c = 0; c < TN; c++)
          acc[r][c] = fmaf(a[r], bv[c], acc[r][c]);
    }
    __syncthreads();
  }

  const int n0 = bn * BN + tx * TN;
  const float4 ev = *reinterpret_cast<const float4*>(ebias + n0);
  #pragma unroll
  for (int r = 0; r < TM; r++) {
    const int brow = bm * BM + ty * TM + r;
    const size_t idx = (size_t)brow * N + n0;
    float c0 = acc[r][0] + ev.x;
    float c1 = acc[r][1] + ev.y;
    float c2 = acc[r][2] + ev.z;
    float c3 = acc[r][3] + ev.w;
    float4 vv = *reinterpret_cast<const float4*>(vst + idx);
    float4 ii = *reinterpret_cast<const float4*>(ist + idx);
    float4 zz;
    lif_update(c0, vv.x, ii.x, zz.x);
    lif_update(c1, vv.y, ii.y, zz.y);
    lif_update(c2, vv.z, ii.z, zz.z);
    lif_update(c3, vv.w, ii.w, zz.w);
    *reinterpret_cast<float4*>(zout + idx) = zz;
    *reinterpret_cast<float4*>(vst  + idx) = vv;
    *reinterpret_cast<float4*>(ist  + idx) = ii;
  }
}

__global__ void out_kernel(const float* __restrict__ z3, const float* __restrict__ Wout,
                           const float* __restrict__ bout, float* __restrict__ vo,
                           float* __restrict__ io, float* __restrict__ acc, float wt) {
  const int idx = blockIdx.x * 256 + threadIdx.x;
  if (idx >= BATCH * ODIM) return;
  const int b = idx >> 1, o = idx & 1;
  const float4* zr = reinterpret_cast<const float4*>(z3 + (size_t)b * H3);
  const float4* wr = reinterpret_cast<const float4*>(Wout + o * H3);
  float s = 0.0f;
  #pragma unroll 4
  for (int k = 0; k < H3 / 4; k++) {
    float4 zv = zr[k], wv = wr[k];
    s += zv.x * wv.x + zv.y * wv.y + zv.z * wv.z + zv.w * wv.w;
  }
  float cin = s + bout[o];
  float v = vo[idx], i = io[idx], z;
  lif_update(cin, v, i, z);
  vo[idx] = v; io[idx] = i;
  acc[idx] += z * wt;
}

extern "C" void kernel_launch(void* const* d_in, const int* in_sizes, int n_in,
                              void* d_out, int out_size, void* d_ws, size_t ws_size,
                              hipStream_t stream) {
  const float* x     = (const float*)d_in[0];
  const float* bni_g = (const float*)d_in[1];
  const float* bni_b = (const float*)d_in[2];
  const float* bni_m = (const float*)d_in[3];
  const float* bni_v = (const float*)d_in[4];
  const float* W1    = (const float*)d_in[5];
  const float* b1    = (const float*)d_in[6];
  const float* bn1_g = (const float*)d_in[7];
  const float* bn1_b = (const float*)d_in[8];
  const float* bn1_m = (const float*)d_in[9];
  const float* bn1_v = (const float*)d_in[10];
  const float* W2    = (const float*)d_in[11];
  const float* b2    = (const float*)d_in[12];
  const float* bn2_g = (const float*)d_in[13];
  const float* bn2_b = (const float*)d_in[14];
  const float* bn2_m = (const float*)d_in[15];
  const float* bn2_v = (const float*)d_in[16];
  const float* W3    = (const float*)d_in[17];
  const float* b3    = (const float*)d_in[18];
  const float* bn3_g = (const float*)d_in[19];
  const float* bn3_b = (const float*)d_in[20];
  const float* bn3_m = (const float*)d_in[21];
  const float* bn3_v = (const float*)d_in[22];
  const float* Wout  = (const float*)d_in[23];
  const float* bout  = (const float*)d_in[24];
  float* out = (float*)d_out;

  float* ws = (float*)d_ws;
  size_t off = 0;
  auto alloc = [&](size_t n) { float* p = ws + off; off += n; return p; };

  // ---- MFMA path layout ----
  float* e1 = alloc(H1);
  float* e2 = alloc(H2);
  float* e3 = alloc(H3);
  float* v1 = alloc((size_t)BATCH * H1);
  float* i1 = alloc((size_t)BATCH * H1);
  float* v2 = alloc((size_t)BATCH * H2);
  float* i2 = alloc((size_t)BATCH * H2);
  float* v3 = alloc((size_t)BATCH * H3);
  float* i3 = alloc((size_t)BATCH * H3);
  float* vo = alloc((size_t)BATCH * ODIM);
  float* io = alloc((size_t)BATCH * ODIM);
  float* xT = alloc((size_t)TDIM * BATCH * FDIM);
  unsigned short* us = (unsigned short*)(ws + off);
  size_t uoff = 0;
  auto ualloc = [&](size_t n) { unsigned short* p = us + uoff; uoff += n; return p; };
  unsigned short* W1p = ualloc((size_t)3 * H1 * FDIM);
  unsigned short* W2p = ualloc((size_t)3 * H2 * H1);
  unsigned short* W3p = ualloc((size_t)3 * H3 * H2);
  unsigned short* z1u = ualloc((size_t)BATCH * H1);
  unsigned short* z2u = ualloc((size_t)BATCH * H2);
  unsigned short* z3u = ualloc((size_t)BATCH * H3);
  unsigned short* Axp = ualloc((size_t)3 * BATCH * FDIM);
  const size_t mfma_needed = off * sizeof(float) + uoff * sizeof(unsigned short);

  const int nstate = BATCH * (2 * H1 + 2 * H2 + 2 * H3 + 2 * ODIM);

  if (ws_size >= mfma_needed) {
    zero_kernel<<<2048, 256, 0, stream>>>(v1, nstate);
    zero_kernel<<<16, 256, 0, stream>>>(out, BATCH * ODIM);

    fold1_mfma<<<H1, 256, 0, stream>>>(W1, b1, bn1_g, bn1_b, bn1_m, bn1_v,
                                       bni_g, bni_b, bni_m, bni_v, W1p, e1);
    foldS_mfma<<<H2, 256, 0, stream>>>(W2, b2, bn2_g, bn2_b, bn2_m, bn2_v, W2p, e2, H2, H1);
    foldS_mfma<<<H3, 256, 0, stream>>>(W3, b3, bn3_g, bn3_b, bn3_m, bn3_v, W3p, e3, H3, H2);
    transpose_kernel<<<dim3(4, 16, 2048), 256, 0, stream>>>(x, xT);
    splitx_kernel<<<BATCH * FDIM / 1024, 256, 0, stream>>>(xT, Axp);

    const dim3 g1(H1 / 64, BATCH / 64);   // (16,32) = 512 blocks
    const dim3 g2(H2 / 32, BATCH / 64);   // (16,32) = 512 blocks
    const dim3 g3(H3 / 32, BATCH / 64);   // (8,32)  = 256 blocks

    for (int t = 0; t < TDIM; t++) {
      mfma_gemm_lif<3, 64, 64><<<g1, 256, 0, stream>>>(Axp, W1p, e1, v1, i1, z1u, H1, FDIM);
      mfma_gemm_lif<1, 64, 32><<<g2, 256, 0, stream>>>(z1u, W2p, e2, v2, i2, z2u, H2, H1);
      mfma_gemm_lif<1, 64, 32><<<g3, 256, 0, stream>>>(z2u, W3p, e3, v3, i3, z3u, H3, H2);
      float wt = (float)std::pow(0.995, (double)(TDIM - 1 - t));
      tail_kernel<<<16 + BATCH * FDIM / 1024, 256, 0, stream>>>(
          z3u, Wout, bout, vo, io, out, wt,
          xT + (size_t)(t + 1) * BATCH * FDIM, Axp, (t + 1 < TDIM) ? 1 : 0);
    }
    return;
  }

  // ---- fp32 fallback (strided GEMM1, no xT) ----
  off = 0;
  float* W1f = alloc((size_t)H1 * FDIM);
  float* W2f = alloc((size_t)H2 * H1);
  float* W3f = alloc((size_t)H3 * H2);
  float* fe1 = alloc(H1);
  float* fe2 = alloc(H2);
  float* fe3 = alloc(H3);
  float* fv1 = alloc((size_t)BATCH * H1);
  float* fi1 = alloc((size_t)BATCH * H1);
  float* fv2 = alloc((size_t)BATCH * H2);
  float* fi2 = alloc((size_t)BATCH * H2);
  float* fv3 = alloc((size_t)BATCH * H3);
  float* fi3 = alloc((size_t)BATCH * H3);
  float* fvo = alloc((size_t)BATCH * ODIM);
  float* fio = alloc((size_t)BATCH * ODIM);
  float* z1  = alloc((size_t)BATCH * H1);
  float* z2  = alloc((size_t)BATCH * H2);
  float* z3  = alloc((size_t)BATCH * H3);

  zero_kernel<<<2048, 256, 0, stream>>>(fv1, nstate);
  zero_kernel<<<16, 256, 0, stream>>>(out, BATCH * ODIM);

  fold1_kernel<<<H1, 256, 0, stream>>>(W1, b1, bn1_g, bn1_b, bn1_m, bn1_v,
                                       bni_g, bni_b, bni_m, bni_v, W1f, fe1);
  foldS_kernel<<<H2, 256, 0, stream>>>(W2, b2, bn2_g, bn2_b, bn2_m, bn2_v, W2f, fe2, H1);
  foldS_kernel<<<H3, 256, 0, stream>>>(W3, b3, bn3_g, bn3_b, bn3_m, bn3_v, W3f, fe3, H2);

  const dim3 fg1(H1 / 64, BATCH / 128);
  const dim3 fg2(H2 / 64, BATCH / 64);
  const dim3 fg3(H3 / 64, BATCH / 64);

  for (int t = 0; t < TDIM; t++) {
    gemm_lif_kernel<8, 4, false><<<fg1, 256, 0, stream>>>(
        x + t, (size_t)FDIM * TDIM, TDIM, W1f, fe1, fv1, fi1, z1, H1, FDIM);
    gemm_lif_kernel<4, 4, true><<<fg2, 256, 0, stream>>>(z1, H1, 1, W2f, fe2, fv2, fi2, z2, H2, H1);
    gemm_lif_kernel<4, 4, true><<<fg3, 256, 0, stream>>>(z2, H2, 1, W3f, fe3, fv3, fi3, z3, H3, H2);
    float wt = (float)std::pow(0.995, (double)(TDIM - 1 - t));
    out_kernel<<<BATCH * ODIM / 256, 256, 0, stream>>>(z3, Wout, bout, fvo, fio, out, wt);
  }
}

// Round 4
// 4831.644 us; speedup vs baseline: 3.1993x; 1.2557x over previous
//
#include <hip/hip_runtime.h>
#include <cmath>

#define BATCH 2048
#define FDIM  512
#define TDIM  100
#define H1    1024
#define H2    512
#define H3    256
#define ODIM  2

typedef __attribute__((ext_vector_type(8))) _Float16 f16x8;
typedef __attribute__((ext_vector_type(4))) _Float16 f16x4;
typedef __attribute__((ext_vector_type(4))) float f32x4;
typedef __attribute__((ext_vector_type(4))) int i32x4;

__device__ __forceinline__ void gl16(const void* g, void* l) {
  __builtin_amdgcn_global_load_lds(
      (const __attribute__((address_space(1))) unsigned int*)g,
      (__attribute__((address_space(3))) unsigned int*)l, 16, 0, 0);
}

// LIF update exactly mirroring the reference order
__device__ __forceinline__ void lif_update(float c, float& v, float& i, float& z) {
  float vd = v + 0.1f * (i - v);
  float id = 0.8f * i;
  z = (vd - 1.0f) > 0.0f ? 1.0f : 0.0f;
  v = (z != 0.0f) ? 0.0f : vd;
  i = id + c;
}

__global__ void zero_kernel(float* __restrict__ p, int n) {
  for (int i = blockIdx.x * blockDim.x + threadIdx.x; i < n; i += gridDim.x * blockDim.x)
    p[i] = 0.0f;
}

// x (B,F,T) -> two fp16 planes of (T,B,F): h = fp16(64*x), m = fp16((64x - h)*4096)
__global__ void transpose_split_kernel(const float* __restrict__ x, _Float16* __restrict__ xp) {
  __shared__ float tile[32][33];
  const int b  = blockIdx.z;
  const int f0 = blockIdx.y * 32;
  const int t0 = blockIdx.x * 32;
  const int tx = threadIdx.x & 31, ty = threadIdx.x >> 5;
  const size_t xb = (size_t)b * FDIM * TDIM;
  #pragma unroll
  for (int r = ty; r < 32; r += 8) {
    int t = t0 + tx;
    if (t < TDIM) tile[r][tx] = x[xb + (size_t)(f0 + r) * TDIM + t];
  }
  __syncthreads();
  const size_t PS = (size_t)TDIM * BATCH * FDIM;
  #pragma unroll
  for (int r = ty; r < 32; r += 8) {
    int t = t0 + r;
    if (t < TDIM) {
      float xa = tile[tx][r] * 64.0f;
      _Float16 h = (_Float16)xa;
      float rr = (xa - (float)h) * 4096.0f;
      size_t o = (size_t)t * BATCH * FDIM + (size_t)b * FDIM + (f0 + tx);
      xp[o]      = h;
      xp[PS + o] = (_Float16)rr;
    }
  }
}

// Layer-1 fold: BN scales folded, then per-row fp16 2-plane split with per-row pow2 scale.
__global__ void fold1_f16(const float* __restrict__ W1, const float* __restrict__ b1,
                          const float* __restrict__ g1, const float* __restrict__ bb1,
                          const float* __restrict__ m1, const float* __restrict__ v1,
                          const float* __restrict__ gi, const float* __restrict__ bi,
                          const float* __restrict__ mi, const float* __restrict__ vi,
                          _Float16* __restrict__ W1p, float* __restrict__ s1,
                          float* __restrict__ e1) {
  __shared__ float swf[FDIM];
  __shared__ float red[8];
  __shared__ float bsw[1];
  const int j = blockIdx.x, tid = threadIdx.x;
  const float sg = g1[j] / sqrtf(v1[j] + 1e-5f);
  float part = 0.0f, pmax = 0.0f;
  for (int f = tid; f < FDIM; f += 256) {
    float si = gi[f] / sqrtf(vi[f] + 1e-5f);
    float h0 = bi[f] - mi[f] * si;
    float w  = W1[j * FDIM + f];
    part += w * h0;
    float wf = w * si * sg;
    swf[f] = wf;
    pmax = fmaxf(pmax, fabsf(wf));
  }
  #pragma unroll
  for (int s = 1; s < 64; s <<= 1) {
    part += __shfl_xor(part, s);
    pmax = fmaxf(pmax, __shfl_xor(pmax, s));
  }
  if ((tid & 63) == 0) { red[tid >> 6] = part; red[4 + (tid >> 6)] = pmax; }
  __syncthreads();
  if (tid == 0) {
    float d = red[0] + red[1] + red[2] + red[3];
    e1[j] = (d + b1[j] - m1[j]) * sg + bb1[j];
    float mx = fmaxf(fmaxf(red[4], red[5]), fmaxf(red[6], red[7]));
    int e = 0;
    if (mx > 0.0f) frexpf(mx, &e);
    s1[j] = exp2f((float)(e - 11));       // combine scale: 2^(e-5) * 2^-6 (A-side 64)
    bsw[0] = exp2f((float)(5 - e));       // |wf * SW| <= 32
  }
  __syncthreads();
  const float SW = bsw[0];
  const size_t PS = (size_t)H1 * FDIM;
  for (int f = tid; f < FDIM; f += 256) {
    float wa = swf[f] * SW;
    _Float16 wh = (_Float16)wa;
    float r = (wa - (float)wh) * 4096.0f;
    W1p[(size_t)j * FDIM + f]      = wh;
    W1p[PS + (size_t)j * FDIM + f] = (_Float16)r;
  }
}

// Layers 2/3 fold: per-row 28-bit integer quantization into 4 signed-7-bit i8 digit planes.
__global__ void foldS_i8(const float* __restrict__ W, const float* __restrict__ b,
                         const float* __restrict__ g, const float* __restrict__ bb,
                         const float* __restrict__ m, const float* __restrict__ v,
                         signed char* __restrict__ Wq, float* __restrict__ qs,
                         float* __restrict__ e, int N, int K) {
  __shared__ float swf[1024];
  __shared__ float red[4];
  __shared__ int bse[1];
  const int j = blockIdx.x, tid = threadIdx.x;
  const float sg = g[j] / sqrtf(v[j] + 1e-5f);
  float pmax = 0.0f;
  for (int k = tid; k < K; k += 256) {
    float wf = W[(size_t)j * K + k] * sg;
    swf[k] = wf;
    pmax = fmaxf(pmax, fabsf(wf));
  }
  #pragma unroll
  for (int s = 1; s < 64; s <<= 1) pmax = fmaxf(pmax, __shfl_xor(pmax, s));
  if ((tid & 63) == 0) red[tid >> 6] = pmax;
  __syncthreads();
  if (tid == 0) {
    float mx = fmaxf(fmaxf(red[0], red[1]), fmaxf(red[2], red[3]));
    int ee = 0;
    if (mx > 0.0f) frexpf(mx, &ee);
    qs[j] = exp2f((float)(ee - 27));
    bse[0] = 27 - ee;
    e[j] = (b[j] - m[j]) * sg + bb[j];
  }
  __syncthreads();
  const double sc = ldexp(1.0, bse[0]);
  const size_t PS = (size_t)N * K;
  for (int k = tid; k < K; k += 256) {
    long D = llround((double)swf[k] * sc);   // |D| <= 2^27
    #pragma unroll
    for (int p = 0; p < 3; p++) {
      int d = (int)(D & 127);
      if (d >= 64) d -= 128;
      Wq[(size_t)p * PS + (size_t)j * K + k] = (signed char)d;
      D = (D - d) >> 7;
    }
    Wq[3 * PS + (size_t)j * K + k] = (signed char)D;  // |D| <= 64
  }
}

// GEMM1: fp16 2-plane x fp16 2-plane (3 pairs, 2 fp32 acc chains) + fused LIF, z -> i8.
__global__ __launch_bounds__(256, 2)
void gemm1_f16_lif(const _Float16* __restrict__ A, const _Float16* __restrict__ Wp,
                   const float* __restrict__ s1, const float* __restrict__ e1,
                   float* __restrict__ vst, float* __restrict__ ist,
                   signed char* __restrict__ zout)
{
  constexpr int BM = 64, BN = 64, K = FDIM, N = H1, BK = 64;
  constexpr int FR = 2, FC = 2, WTM = 32, WTN = 32;
  __shared__ __align__(16) _Float16 As[2][BM][BK];
  __shared__ __align__(16) _Float16 Bs[2][BN][BK];
  const int tid = threadIdx.x, lane = tid & 63, wid = tid >> 6;
  const int wr = wid >> 1, wc = wid & 1;
  const int l16 = lane & 15, lq = lane >> 4;
  const int bnk = blockIdx.x, bmk = blockIdx.y;
  const size_t APS = (size_t)TDIM * BATCH * FDIM;   // plane stride of Xp
  const size_t WPS = (size_t)N * K;
  const int lrow8 = lane >> 3, lslot = lane & 7;

  f32x4 accA[FR][FC] = {}, accB[FR][FC] = {};

  auto stage = [&](int it) {
    const int k0 = it * BK;
    #pragma unroll
    for (int q = 0; q < 4; ++q) {           // 2 planes * 8 row-groups / 4 waves
      int i = q * 4 + wid;
      int s = i >> 3, r0 = (i & 7) * 8;
      int row = r0 + lrow8;
      int ss = lslot ^ (row & 7);
      gl16(A + (size_t)s * APS + (size_t)(bmk * BM + row) * K + k0 + ss * 8, &As[s][r0][0]);
    }
    #pragma unroll
    for (int q = 0; q < 4; ++q) {
      int i = q * 4 + wid;
      int s = i >> 3, r0 = (i & 7) * 8;
      int row = r0 + lrow8;
      int ss = lslot ^ (row & 7);
      gl16(Wp + (size_t)s * WPS + (size_t)(bnk * BN + row) * K + k0 + ss * 8, &Bs[s][r0][0]);
    }
  };

  stage(0);
  __syncthreads();
  constexpr int NK = K / BK;
  for (int it = 0; it < NK; ++it) {
    f16x8 af[2][2][FR], bf[2][2][FC];
    #pragma unroll
    for (int kh = 0; kh < 2; ++kh) {
      #pragma unroll
      for (int s = 0; s < 2; ++s) {
        #pragma unroll
        for (int fr = 0; fr < FR; ++fr) {
          int row = wr * WTM + fr * 16 + l16;
          int slot = ((kh << 2) | lq) ^ (row & 7);
          af[kh][s][fr] = *reinterpret_cast<const f16x8*>(&As[s][row][slot * 8]);
        }
        #pragma unroll
        for (int fc = 0; fc < FC; ++fc) {
          int row = wc * WTN + fc * 16 + l16;
          int slot = ((kh << 2) | lq) ^ (row & 7);
          bf[kh][s][fc] = *reinterpret_cast<const f16x8*>(&Bs[s][row][slot * 8]);
        }
      }
    }
    __syncthreads();
    if (it + 1 < NK) stage(it + 1);
    #pragma unroll
    for (int kh = 0; kh < 2; ++kh)
      #pragma unroll
      for (int fr = 0; fr < FR; ++fr)
        #pragma unroll
        for (int fc = 0; fc < FC; ++fc) {
          accA[fr][fc] = __builtin_amdgcn_mfma_f32_16x16x32_f16(af[kh][0][fr], bf[kh][0][fc], accA[fr][fc], 0, 0, 0);
          accB[fr][fc] = __builtin_amdgcn_mfma_f32_16x16x32_f16(af[kh][0][fr], bf[kh][1][fc], accB[fr][fc], 0, 0, 0);
          accB[fr][fc] = __builtin_amdgcn_mfma_f32_16x16x32_f16(af[kh][1][fr], bf[kh][0][fc], accB[fr][fc], 0, 0, 0);
        }
    __syncthreads();
  }

  #pragma unroll
  for (int fc = 0; fc < FC; ++fc) {
    const int n = bnk * BN + wc * WTN + fc * 16 + l16;
    const float eb = e1[n], sn = s1[n];
    #pragma unroll
    for (int fr = 0; fr < FR; ++fr) {
      const int row0 = bmk * BM + wr * WTM + fr * 16 + lq * 4;
      #pragma unroll
      for (int r = 0; r < 4; ++r) {
        const size_t idx = (size_t)(row0 + r) * N + n;
        float c = sn * (accA[fr][fc][r] + 0.000244140625f * accB[fr][fc][r]) + eb;
        float v = vst[idx], ii = ist[idx], z;
        lif_update(c, v, ii, z);
        vst[idx] = v; ist[idx] = ii;
        zout[idx] = (signed char)(z != 0.0f ? 1 : 0);
      }
    }
  }
}

// GEMM2/3: exact i8 spikes x 4 i8 digit planes (i32 accumulate) + fused LIF, z -> i8.
template<int BM, int BN>
__global__ __launch_bounds__(256, 2)
void gemmS_i8_lif(const signed char* __restrict__ A, const signed char* __restrict__ Wq,
                  const float* __restrict__ qs, const float* __restrict__ eb_,
                  float* __restrict__ vst, float* __restrict__ ist,
                  signed char* __restrict__ zout, const int N, const int K)
{
  constexpr int BKI = 128;
  constexpr int WTM = BM / 2, WTN = BN / 2, FR = WTM / 16, FC = WTN / 16;
  constexpr int RA = BM / 8, RB = BN / 8;
  __shared__ __align__(16) signed char As[BM][BKI];
  __shared__ __align__(16) signed char Bs[4][BN][BKI];
  const int tid = threadIdx.x, lane = tid & 63, wid = tid >> 6;
  const int wr = wid >> 1, wc = wid & 1;
  const int l16 = lane & 15, lq = lane >> 4;
  const int bnk = blockIdx.x, bmk = blockIdx.y;
  const size_t WPS = (size_t)N * K;
  const int lrow8 = lane >> 3, lslot = lane & 7;

  i32x4 acc[4][FR][FC] = {};

  auto stage = [&](int it) {
    const int k0 = it * BKI;
    #pragma unroll
    for (int q = 0; q < RA / 4; ++q) {
      int i = q * 4 + wid;
      int r0 = i * 8, row = r0 + lrow8;
      int ss = lslot ^ (row & 7);
      gl16(A + (size_t)(bmk * BM + row) * K + k0 + ss * 16, &As[r0][0]);
    }
    #pragma unroll
    for (int q = 0; q < RB; ++q) {           // 4 planes * RB row-groups / 4 waves
      int i = q * 4 + wid;
      int s = i / RB, r0 = (i % RB) * 8, row = r0 + lrow8;
      int ss = lslot ^ (row & 7);
      gl16(Wq + (size_t)s * WPS + (size_t)(bnk * BN + row) * K + k0 + ss * 16, &Bs[s][r0][0]);
    }
  };

  stage(0);
  __syncthreads();
  const int NK = K / BKI;
  for (int it = 0; it < NK; ++it) {
    i32x4 av[2][FR], bv[2][4][FC];
    #pragma unroll
    for (int kh = 0; kh < 2; ++kh) {
      #pragma unroll
      for (int fr = 0; fr < FR; ++fr) {
        int row = wr * WTM + fr * 16 + l16;
        int slot = ((kh << 2) | lq) ^ (row & 7);
        av[kh][fr] = *reinterpret_cast<const i32x4*>(&As[row][slot * 16]);
      }
      #pragma unroll
      for (int s = 0; s < 4; ++s)
        #pragma unroll
        for (int fc = 0; fc < FC; ++fc) {
          int row = wc * WTN + fc * 16 + l16;
          int slot = ((kh << 2) | lq) ^ (row & 7);
          bv[kh][s][fc] = *reinterpret_cast<const i32x4*>(&Bs[s][row][slot * 16]);
        }
    }
    __syncthreads();
    if (it + 1 < NK) stage(it + 1);
    #pragma unroll
    for (int kh = 0; kh < 2; ++kh)
      #pragma unroll
      for (int s = 0; s < 4; ++s)
        #pragma unroll
        for (int fr = 0; fr < FR; ++fr)
          #pragma unroll
          for (int fc = 0; fc < FC; ++fc)
            acc[s][fr][fc] = __builtin_amdgcn_mfma_i32_16x16x64_i8(av[kh][fr], bv[kh][s][fc], acc[s][fr][fc], 0, 0, 0);
    __syncthreads();
  }

  #pragma unroll
  for (int fc = 0; fc < FC; ++fc) {
    const int n = bnk * BN + wc * WTN + fc * 16 + l16;
    const float qv = qs[n], eb = eb_[n];
    #pragma unroll
    for (int fr = 0; fr < FR; ++fr) {
      const int row0 = bmk * BM + wr * WTM + fr * 16 + lq * 4;
      #pragma unroll
      for (int r = 0; r < 4; ++r) {
        const size_t idx = (size_t)(row0 + r) * N + n;
        int slo = acc[0][fr][fc][r] + (acc[1][fr][fc][r] << 7) + (acc[2][fr][fc][r] << 14);
        float c = qv * fmaf(2097152.0f, (float)acc[3][fr][fc][r], (float)slo) + eb;
        float v = vst[idx], ii = ist[idx], z;
        lif_update(c, v, ii, z);
        vst[idx] = v; ist[idx] = ii;
        zout[idx] = (signed char)(z != 0.0f ? 1 : 0);
      }
    }
  }
}

// Output layer: co = z3 @ Wout^T + bout, LIF, acc += z*wt  (z3 in i8)
__global__ void out_tail(const signed char* __restrict__ z3, const float* __restrict__ Wout,
                         const float* __restrict__ bout, float* __restrict__ vo,
                         float* __restrict__ io, float* __restrict__ acc, float wt) {
  const int idx = blockIdx.x * 256 + threadIdx.x;  // 0..4095
  if (idx >= BATCH * ODIM) return;
  const int b = idx >> 1, o = idx & 1;
  const signed char* zr = z3 + (size_t)b * H3;
  const float* wr = Wout + (size_t)o * H3;
  float s = 0.0f;
  for (int k0 = 0; k0 < H3; k0 += 16) {
    i32x4 zw = *reinterpret_cast<const i32x4*>(zr + k0);
    #pragma unroll
    for (int j = 0; j < 16; j++) {
      float zf = (float)((zw[j >> 2] >> ((j & 3) * 8)) & 1);
      s = fmaf(zf, wr[k0 + j], s);
    }
  }
  float cin = s + bout[o];
  float v = vo[idx], i = io[idx], z;
  lif_update(cin, v, i, z);
  vo[idx] = v; io[idx] = i;
  acc[idx] += z * wt;
}

// ---------------- fp32 fallback path (round-1 kernels) ----------------
__global__ void fold1_kernel(const float* __restrict__ W1, const float* __restrict__ b1,
                             const float* __restrict__ g1, const float* __restrict__ bb1,
                             const float* __restrict__ m1, const float* __restrict__ v1,
                             const float* __restrict__ gi, const float* __restrict__ bi,
                             const float* __restrict__ mi, const float* __restrict__ vi,
                             float* __restrict__ W1f, float* __restrict__ e1) {
  const int j = blockIdx.x;
  const int tid = threadIdx.x;
  const float sg = g1[j] / sqrtf(v1[j] + 1e-5f);
  float part = 0.0f;
  for (int f = tid; f < FDIM; f += 256) {
    float si = gi[f] / sqrtf(vi[f] + 1e-5f);
    float h0 = bi[f] - mi[f] * si;
    float w  = W1[j * FDIM + f];
    part += w * h0;
    W1f[j * FDIM + f] = w * si * sg;
  }
  #pragma unroll
  for (int m = 1; m < 64; m <<= 1) part += __shfl_xor(part, m);
  __shared__ float red[4];
  if ((tid & 63) == 0) red[tid >> 6] = part;
  __syncthreads();
  if (tid == 0) {
    float d = red[0] + red[1] + red[2] + red[3];
    e1[j] = (d + b1[j] - m1[j]) * sg + bb1[j];
  }
}

__global__ void foldS_kernel(const float* __restrict__ W, const float* __restrict__ b,
                             const float* __restrict__ g, const float* __restrict__ bb,
                             const float* __restrict__ m, const float* __restrict__ v,
                             float* __restrict__ Wf, float* __restrict__ e, int K) {
  const int j = blockIdx.x;
  const float sg = g[j] / sqrtf(v[j] + 1e-5f);
  for (int k = threadIdx.x; k < K; k += 256)
    Wf[j * K + k] = W[j * K + k] * sg;
  if (threadIdx.x == 0) e[j] = (b[j] - m[j]) * sg + bb[j];
}

template<int TM, int TN, bool CONTIG>
__global__ __launch_bounds__(256, 2)
void gemm_lif_kernel(const float* __restrict__ A, size_t ars, size_t acs,
                     const float* __restrict__ W, const float* __restrict__ ebias,
                     float* __restrict__ vst, float* __restrict__ ist,
                     float* __restrict__ zout, int N, int K)
{
  constexpr int BK = 16;
  constexpr int BM = 16 * TM;
  constexpr int BN = 16 * TN;
  __shared__ float As[BK][BM];
  __shared__ float Bs[BK][BN];
  const int tid = threadIdx.x;
  const int tx = tid & 15, ty = tid >> 4;
  const int bn = blockIdx.x, bm = blockIdx.y;
  const float* Ablk = A + (size_t)bm * BM * ars;
  const float* Wblk = W + (size_t)bn * BN * (size_t)K;

  float acc[TM][TN];
  #pragma unroll
  for (int r = 0; r < TM; r++)
    #pragma unroll
    for (int c = 0; c < TN; c++) acc[r][c] = 0.0f;

  for (int k0 = 0; k0 < K; k0 += BK) {
    if (CONTIG) {
      constexpr int A4 = BM * BK / 4;
      #pragma unroll
      for (int q = 0; q < A4 / 256; q++) {
        int idx = q * 256 + tid;
        int r = idx >> 2;
        int kq = (idx & 3) << 2;
        float4 val = *reinterpret_cast<const float4*>(Ablk + (size_t)r * ars + (size_t)(k0 + kq));
        As[kq + 0][r] = val.x; As[kq + 1][r] = val.y;
        As[kq + 2][r] = val.z; As[kq + 3][r] = val.w;
      }
    } else {
      #pragma unroll
      for (int q = 0; q < BM * BK / 256; q++) {
        int idx = q * 256 + tid;
        int r = idx >> 4;
        int kk = idx & 15;
        As[kk][r] = Ablk[(size_t)r * ars + (size_t)(k0 + kk) * acs];
      }
    }
    {
      int n  = tid >> 2;
      int kq = (tid & 3) << 2;
      float4 val = *reinterpret_cast<const float4*>(Wblk + (size_t)n * K + (size_t)(k0 + kq));
      Bs[kq + 0][n] = val.x; Bs[kq + 1][n] = val.y;
      Bs[kq + 2][n] = val.z; Bs[kq + 3][n] = val.w;
    }
    __syncthreads();
    #pragma unroll
    for (int kk = 0; kk < BK; kk++) {
      float a[TM], bv[TN];
      const float4* ap = reinterpret_cast<const float4*>(&As[kk][ty * TM]);
      *reinterpret_cast<float4*>(&a[0]) = ap[0];
      if (TM == 8) *reinterpret_cast<float4*>(&a[4]) = ap[1];
      *reinterpret_cast<float4*>(&bv[0]) = *reinterpret_cast<const float4*>(&Bs[kk][tx * TN]);
      #pragma unroll
      for (int r = 0; r < TM; r++)
        #pragma unroll
        for (int c = 0; c < TN; c++)
          acc[r][c] = fmaf(a[r], bv[c], acc[r][c]);
    }
    __syncthreads();
  }

  const int n0 = bn * BN + tx * TN;
  const float4 ev = *reinterpret_cast<const float4*>(ebias + n0);
  #pragma unroll
  for (int r = 0; r < TM; r++) {
    const int brow = bm * BM + ty * TM + r;
    const size_t idx = (size_t)brow * N + n0;
    float c0 = acc[r][0] + ev.x;
    float c1 = acc[r][1] + ev.y;
    float c2 = acc[r][2] + ev.z;
    float c3 = acc[r][3] + ev.w;
    float4 vv = *reinterpret_cast<const float4*>(vst + idx);
    float4 ii = *reinterpret_cast<const float4*>(ist + idx);
    float4 zz;
    lif_update(c0, vv.x, ii.x, zz.x);
    lif_update(c1, vv.y, ii.y, zz.y);
    lif_update(c2, vv.z, ii.z, zz.z);
    lif_update(c3, vv.w, ii.w, zz.w);
    *reinterpret_cast<float4*>(zout + idx) = zz;
    *reinterpret_cast<float4*>(vst  + idx) = vv;
    *reinterpret_cast<float4*>(ist  + idx) = ii;
  }
}

__global__ void out_kernel(const float* __restrict__ z3, const float* __restrict__ Wout,
                           const float* __restrict__ bout, float* __restrict__ vo,
                           float* __restrict__ io, float* __restrict__ acc, float wt) {
  const int idx = blockIdx.x * 256 + threadIdx.x;
  if (idx >= BATCH * ODIM) return;
  const int b = idx >> 1, o = idx & 1;
  const float4* zr = reinterpret_cast<const float4*>(z3 + (size_t)b * H3);
  const float4* wr = reinterpret_cast<const float4*>(Wout + o * H3);
  float s = 0.0f;
  #pragma unroll 4
  for (int k = 0; k < H3 / 4; k++) {
    float4 zv = zr[k], wv = wr[k];
    s += zv.x * wv.x + zv.y * wv.y + zv.z * wv.z + zv.w * wv.w;
  }
  float cin = s + bout[o];
  float v = vo[idx], i = io[idx], z;
  lif_update(cin, v, i, z);
  vo[idx] = v; io[idx] = i;
  acc[idx] += z * wt;
}

extern "C" void kernel_launch(void* const* d_in, const int* in_sizes, int n_in,
                              void* d_out, int out_size, void* d_ws, size_t ws_size,
                              hipStream_t stream) {
  const float* x     = (const float*)d_in[0];
  const float* bni_g = (const float*)d_in[1];
  const float* bni_b = (const float*)d_in[2];
  const float* bni_m = (const float*)d_in[3];
  const float* bni_v = (const float*)d_in[4];
  const float* W1    = (const float*)d_in[5];
  const float* b1    = (const float*)d_in[6];
  const float* bn1_g = (const float*)d_in[7];
  const float* bn1_b = (const float*)d_in[8];
  const float* bn1_m = (const float*)d_in[9];
  const float* bn1_v = (const float*)d_in[10];
  const float* W2    = (const float*)d_in[11];
  const float* b2    = (const float*)d_in[12];
  const float* bn2_g = (const float*)d_in[13];
  const float* bn2_b = (const float*)d_in[14];
  const float* bn2_m = (const float*)d_in[15];
  const float* bn2_v = (const float*)d_in[16];
  const float* W3    = (const float*)d_in[17];
  const float* b3    = (const float*)d_in[18];
  const float* bn3_g = (const float*)d_in[19];
  const float* bn3_b = (const float*)d_in[20];
  const float* bn3_m = (const float*)d_in[21];
  const float* bn3_v = (const float*)d_in[22];
  const float* Wout  = (const float*)d_in[23];
  const float* bout  = (const float*)d_in[24];
  float* out = (float*)d_out;

  float* ws = (float*)d_ws;
  size_t off = 0;
  auto alloc = [&](size_t n) { float* p = ws + off; off += n; return p; };

  // ---- MFMA path layout ----
  float* e1 = alloc(H1);
  float* e2 = alloc(H2);
  float* e3 = alloc(H3);
  float* s1 = alloc(H1);
  float* q2 = alloc(H2);
  float* q3 = alloc(H3);
  float* v1 = alloc((size_t)BATCH * H1);
  float* i1 = alloc((size_t)BATCH * H1);
  float* v2 = alloc((size_t)BATCH * H2);
  float* i2 = alloc((size_t)BATCH * H2);
  float* v3 = alloc((size_t)BATCH * H3);
  float* i3 = alloc((size_t)BATCH * H3);
  float* vo = alloc((size_t)BATCH * ODIM);
  float* io = alloc((size_t)BATCH * ODIM);
  _Float16* hs = (_Float16*)(ws + off);
  size_t hoff = 0;
  auto halloc = [&](size_t n) { _Float16* p = hs + hoff; hoff += n; return p; };
  _Float16* Xp  = halloc((size_t)2 * TDIM * BATCH * FDIM);
  _Float16* W1p = halloc((size_t)2 * H1 * FDIM);
  signed char* bs = (signed char*)(hs + hoff);
  size_t boff = 0;
  auto balloc = [&](size_t n) { signed char* p = bs + boff; boff += n; return p; };
  signed char* W2q = balloc((size_t)4 * H2 * H1);
  signed char* W3q = balloc((size_t)4 * H3 * H2);
  signed char* z1  = balloc((size_t)BATCH * H1);
  signed char* z2  = balloc((size_t)BATCH * H2);
  signed char* z3  = balloc((size_t)BATCH * H3);
  const size_t mfma_needed = off * sizeof(float) + hoff * sizeof(_Float16) + boff;

  const int nstate = BATCH * (2 * H1 + 2 * H2 + 2 * H3 + 2 * ODIM);

  if (ws_size >= mfma_needed) {
    zero_kernel<<<2048, 256, 0, stream>>>(v1, nstate);
    zero_kernel<<<16, 256, 0, stream>>>(out, BATCH * ODIM);

    fold1_f16<<<H1, 256, 0, stream>>>(W1, b1, bn1_g, bn1_b, bn1_m, bn1_v,
                                      bni_g, bni_b, bni_m, bni_v, W1p, s1, e1);
    foldS_i8<<<H2, 256, 0, stream>>>(W2, b2, bn2_g, bn2_b, bn2_m, bn2_v, W2q, q2, e2, H2, H1);
    foldS_i8<<<H3, 256, 0, stream>>>(W3, b3, bn3_g, bn3_b, bn3_m, bn3_v, W3q, q3, e3, H3, H2);
    transpose_split_kernel<<<dim3(4, 16, 2048), 256, 0, stream>>>(x, Xp);

    const dim3 g1(H1 / 64, BATCH / 64);   // (16,32)
    const dim3 g2(H2 / 32, BATCH / 64);   // (16,32)
    const dim3 g3(H3 / 32, BATCH / 32);   // (8,64)

    for (int t = 0; t < TDIM; t++) {
      gemm1_f16_lif<<<g1, 256, 0, stream>>>(Xp + (size_t)t * BATCH * FDIM, W1p, s1, e1,
                                            v1, i1, z1);
      gemmS_i8_lif<64, 32><<<g2, 256, 0, stream>>>(z1, W2q, q2, e2, v2, i2, z2, H2, H1);
      gemmS_i8_lif<32, 32><<<g3, 256, 0, stream>>>(z2, W3q, q3, e3, v3, i3, z3, H3, H2);
      float wt = (float)std::pow(0.995, (double)(TDIM - 1 - t));
      out_tail<<<16, 256, 0, stream>>>(z3, Wout, bout, vo, io, out, wt);
    }
    return;
  }

  // ---- fp32 fallback (strided GEMM1, no transpose) ----
  off = 0;
  float* W1f = alloc((size_t)H1 * FDIM);
  float* W2f = alloc((size_t)H2 * H1);
  float* W3f = alloc((size_t)H3 * H2);
  float* fe1 = alloc(H1);
  float* fe2 = alloc(H2);
  float* fe3 = alloc(H3);
  float* fv1 = alloc((size_t)BATCH * H1);
  float* fi1 = alloc((size_t)BATCH * H1);
  float* fv2 = alloc((size_t)BATCH * H2);
  float* fi2 = alloc((size_t)BATCH * H2);
  float* fv3 = alloc((size_t)BATCH * H3);
  float* fi3 = alloc((size_t)BATCH * H3);
  float* fvo = alloc((size_t)BATCH * ODIM);
  float* fio = alloc((size_t)BATCH * ODIM);
  float* fz1 = alloc((size_t)BATCH * H1);
  float* fz2 = alloc((size_t)BATCH * H2);
  float* fz3 = alloc((size_t)BATCH * H3);

  zero_kernel<<<2048, 256, 0, stream>>>(fv1, nstate);
  zero_kernel<<<16, 256, 0, stream>>>(out, BATCH * ODIM);

  fold1_kernel<<<H1, 256, 0, stream>>>(W1, b1, bn1_g, bn1_b, bn1_m, bn1_v,
                                       bni_g, bni_b, bni_m, bni_v, W1f, fe1);
  foldS_kernel<<<H2, 256, 0, stream>>>(W2, b2, bn2_g, bn2_b, bn2_m, bn2_v, W2f, fe2, H1);
  foldS_kernel<<<H3, 256, 0, stream>>>(W3, b3, bn3_g, bn3_b, bn3_m, bn3_v, W3f, fe3, H2);

  const dim3 fg1(H1 / 64, BATCH / 128);
  const dim3 fg2(H2 / 64, BATCH / 64);
  const dim3 fg3(H3 / 64, BATCH / 64);

  for (int t = 0; t < TDIM; t++) {
    gemm_lif_kernel<8, 4, false><<<fg1, 256, 0, stream>>>(
        x + t, (size_t)FDIM * TDIM, TDIM, W1f, fe1, fv1, fi1, fz1, H1, FDIM);
    gemm_lif_kernel<4, 4, true><<<fg2, 256, 0, stream>>>(fz1, H1, 1, W2f, fe2, fv2, fi2, fz2, H2, H1);
    gemm_lif_kernel<4, 4, true><<<fg3, 256, 0, stream>>>(fz2, H2, 1, W3f, fe3, fv3, fi3, fz3, H3, H2);
    float wt = (float)std::pow(0.995, (double)(TDIM - 1 - t));
    out_kernel<<<BATCH * ODIM / 256, 256, 0, stream>>>(fz3, Wout, bout, fvo, fio, out, wt);
  }
}

// Round 5
// 3262.492 us; speedup vs baseline: 4.7380x; 1.4810x over previous
//
#include <hip/hip_runtime.h>
#include <cmath>

#define BATCH 2048
#define FDIM  512
#define TDIM  100
#define H1    1024
#define H2    512
#define H3    256
#define ODIM  2

typedef __attribute__((ext_vector_type(8))) _Float16 f16x8;
typedef __attribute__((ext_vector_type(4))) float f32x4;
typedef __attribute__((ext_vector_type(4))) int i32x4;

__device__ __forceinline__ void gl16(const void* g, void* l) {
  __builtin_amdgcn_global_load_lds(
      (const __attribute__((address_space(1))) unsigned int*)g,
      (__attribute__((address_space(3))) unsigned int*)l, 16, 0, 0);
}

// LIF update exactly mirroring the reference order
__device__ __forceinline__ void lif_update(float c, float& v, float& i, float& z) {
  float vd = v + 0.1f * (i - v);
  float id = 0.8f * i;
  z = (vd - 1.0f) > 0.0f ? 1.0f : 0.0f;
  v = (z != 0.0f) ? 0.0f : vd;
  i = id + c;
}

__global__ void zero_kernel(float* __restrict__ p, int n) {
  for (int i = blockIdx.x * blockDim.x + threadIdx.x; i < n; i += gridDim.x * blockDim.x)
    p[i] = 0.0f;
}

// x (B,F,T) -> two fp16 planes of (T,B,F): h = fp16(64*x), m = fp16((64x - h)*4096)
__global__ void transpose_split_kernel(const float* __restrict__ x, _Float16* __restrict__ xp) {
  __shared__ float tile[32][33];
  const int b  = blockIdx.z;
  const int f0 = blockIdx.y * 32;
  const int t0 = blockIdx.x * 32;
  const int tx = threadIdx.x & 31, ty = threadIdx.x >> 5;
  const size_t xb = (size_t)b * FDIM * TDIM;
  #pragma unroll
  for (int r = ty; r < 32; r += 8) {
    int t = t0 + tx;
    if (t < TDIM) tile[r][tx] = x[xb + (size_t)(f0 + r) * TDIM + t];
  }
  __syncthreads();
  const size_t PS = (size_t)TDIM * BATCH * FDIM;
  #pragma unroll
  for (int r = ty; r < 32; r += 8) {
    int t = t0 + r;
    if (t < TDIM) {
      float xa = tile[tx][r] * 64.0f;
      _Float16 h = (_Float16)xa;
      float rr = (xa - (float)h) * 4096.0f;
      size_t o = (size_t)t * BATCH * FDIM + (size_t)b * FDIM + (f0 + tx);
      xp[o]      = h;
      xp[PS + o] = (_Float16)rr;
    }
  }
}

// Layer-1 fold: BN scales folded, then per-row fp16 2-plane split with per-row pow2 scale.
__global__ void fold1_f16(const float* __restrict__ W1, const float* __restrict__ b1,
                          const float* __restrict__ g1, const float* __restrict__ bb1,
                          const float* __restrict__ m1, const float* __restrict__ v1,
                          const float* __restrict__ gi, const float* __restrict__ bi,
                          const float* __restrict__ mi, const float* __restrict__ vi,
                          _Float16* __restrict__ W1p, float* __restrict__ s1,
                          float* __restrict__ e1) {
  __shared__ float swf[FDIM];
  __shared__ float red[8];
  __shared__ float bsw[1];
  const int j = blockIdx.x, tid = threadIdx.x;
  const float sg = g1[j] / sqrtf(v1[j] + 1e-5f);
  float part = 0.0f, pmax = 0.0f;
  for (int f = tid; f < FDIM; f += 256) {
    float si = gi[f] / sqrtf(vi[f] + 1e-5f);
    float h0 = bi[f] - mi[f] * si;
    float w  = W1[j * FDIM + f];
    part += w * h0;
    float wf = w * si * sg;
    swf[f] = wf;
    pmax = fmaxf(pmax, fabsf(wf));
  }
  #pragma unroll
  for (int s = 1; s < 64; s <<= 1) {
    part += __shfl_xor(part, s);
    pmax = fmaxf(pmax, __shfl_xor(pmax, s));
  }
  if ((tid & 63) == 0) { red[tid >> 6] = part; red[4 + (tid >> 6)] = pmax; }
  __syncthreads();
  if (tid == 0) {
    float d = red[0] + red[1] + red[2] + red[3];
    e1[j] = (d + b1[j] - m1[j]) * sg + bb1[j];
    float mx = fmaxf(fmaxf(red[4], red[5]), fmaxf(red[6], red[7]));
    int e = 0;
    if (mx > 0.0f) frexpf(mx, &e);
    s1[j] = exp2f((float)(e - 11));       // combine scale: 2^(e-5) * 2^-6 (A-side 64)
    bsw[0] = exp2f((float)(5 - e));       // |wf * SW| <= 32
  }
  __syncthreads();
  const float SW = bsw[0];
  const size_t PS = (size_t)H1 * FDIM;
  for (int f = tid; f < FDIM; f += 256) {
    float wa = swf[f] * SW;
    _Float16 wh = (_Float16)wa;
    float r = (wa - (float)wh) * 4096.0f;
    W1p[(size_t)j * FDIM + f]      = wh;
    W1p[PS + (size_t)j * FDIM + f] = (_Float16)r;
  }
}

// Layers 2/3 fold: per-row 28-bit integer quantization into 4 signed-7-bit i8 digit planes.
__global__ void foldS_i8(const float* __restrict__ W, const float* __restrict__ b,
                         const float* __restrict__ g, const float* __restrict__ bb,
                         const float* __restrict__ m, const float* __restrict__ v,
                         signed char* __restrict__ Wq, float* __restrict__ qs,
                         float* __restrict__ e, int N, int K) {
  __shared__ float swf[1024];
  __shared__ float red[4];
  __shared__ int bse[1];
  const int j = blockIdx.x, tid = threadIdx.x;
  const float sg = g[j] / sqrtf(v[j] + 1e-5f);
  float pmax = 0.0f;
  for (int k = tid; k < K; k += 256) {
    float wf = W[(size_t)j * K + k] * sg;
    swf[k] = wf;
    pmax = fmaxf(pmax, fabsf(wf));
  }
  #pragma unroll
  for (int s = 1; s < 64; s <<= 1) pmax = fmaxf(pmax, __shfl_xor(pmax, s));
  if ((tid & 63) == 0) red[tid >> 6] = pmax;
  __syncthreads();
  if (tid == 0) {
    float mx = fmaxf(fmaxf(red[0], red[1]), fmaxf(red[2], red[3]));
    int ee = 0;
    if (mx > 0.0f) frexpf(mx, &ee);
    qs[j] = exp2f((float)(ee - 27));
    bse[0] = 27 - ee;
    e[j] = (b[j] - m[j]) * sg + bb[j];
  }
  __syncthreads();
  const double sc = ldexp(1.0, bse[0]);
  const size_t PS = (size_t)N * K;
  for (int k = tid; k < K; k += 256) {
    long D = llround((double)swf[k] * sc);   // |D| <= 2^27
    #pragma unroll
    for (int p = 0; p < 3; p++) {
      int d = (int)(D & 127);
      if (d >= 64) d -= 128;
      Wq[(size_t)p * PS + (size_t)j * K + k] = (signed char)d;
      D = (D - d) >> 7;
    }
    Wq[3 * PS + (size_t)j * K + k] = (signed char)D;  // |D| <= 64
  }
}

// ---- role bodies (verbatim round-4 inner loops, smem passed in) ----

// GEMM1: fp16 2-plane x fp16 2-plane (3 pairs) + fused LIF, z -> i8.
__device__ __forceinline__ void g1_body(unsigned char* smem, int bnk, int bmk,
    const _Float16* __restrict__ A, const _Float16* __restrict__ Wp,
    const float* __restrict__ s1, const float* __restrict__ e1,
    float* __restrict__ vst, float* __restrict__ ist, signed char* __restrict__ zout)
{
  constexpr int BM = 64, BN = 64, K = FDIM, N = H1, BK = 64;
  constexpr int FR = 2, FC = 2, WTM = 32, WTN = 32;
  typedef _Float16 (*F16T)[BM][BK];
  F16T As = (F16T)smem;                                    // [2][64][64]
  F16T Bs = (F16T)(smem + 2 * BM * BK * sizeof(_Float16)); // [2][64][64]
  const int tid = threadIdx.x, lane = tid & 63, wid = tid >> 6;
  const int wr = wid >> 1, wc = wid & 1;
  const int l16 = lane & 15, lq = lane >> 4;
  const size_t APS = (size_t)TDIM * BATCH * FDIM;
  const size_t WPS = (size_t)N * K;
  const int lrow8 = lane >> 3, lslot = lane & 7;

  f32x4 accA[FR][FC] = {}, accB[FR][FC] = {};

  auto stage = [&](int it) {
    const int k0 = it * BK;
    #pragma unroll
    for (int q = 0; q < 4; ++q) {
      int i = q * 4 + wid;
      int s = i >> 3, r0 = (i & 7) * 8;
      int row = r0 + lrow8;
      int ss = lslot ^ (row & 7);
      gl16(A + (size_t)s * APS + (size_t)(bmk * BM + row) * K + k0 + ss * 8, &As[s][r0][0]);
    }
    #pragma unroll
    for (int q = 0; q < 4; ++q) {
      int i = q * 4 + wid;
      int s = i >> 3, r0 = (i & 7) * 8;
      int row = r0 + lrow8;
      int ss = lslot ^ (row & 7);
      gl16(Wp + (size_t)s * WPS + (size_t)(bnk * BN + row) * K + k0 + ss * 8, &Bs[s][r0][0]);
    }
  };

  stage(0);
  __syncthreads();
  constexpr int NK = K / BK;
  for (int it = 0; it < NK; ++it) {
    f16x8 af[2][2][FR], bf[2][2][FC];
    #pragma unroll
    for (int kh = 0; kh < 2; ++kh) {
      #pragma unroll
      for (int s = 0; s < 2; ++s) {
        #pragma unroll
        for (int fr = 0; fr < FR; ++fr) {
          int row = wr * WTM + fr * 16 + l16;
          int slot = ((kh << 2) | lq) ^ (row & 7);
          af[kh][s][fr] = *reinterpret_cast<const f16x8*>(&As[s][row][slot * 8]);
        }
        #pragma unroll
        for (int fc = 0; fc < FC; ++fc) {
          int row = wc * WTN + fc * 16 + l16;
          int slot = ((kh << 2) | lq) ^ (row & 7);
          bf[kh][s][fc] = *reinterpret_cast<const f16x8*>(&Bs[s][row][slot * 8]);
        }
      }
    }
    __syncthreads();
    if (it + 1 < NK) stage(it + 1);
    #pragma unroll
    for (int kh = 0; kh < 2; ++kh)
      #pragma unroll
      for (int fr = 0; fr < FR; ++fr)
        #pragma unroll
        for (int fc = 0; fc < FC; ++fc) {
          accA[fr][fc] = __builtin_amdgcn_mfma_f32_16x16x32_f16(af[kh][0][fr], bf[kh][0][fc], accA[fr][fc], 0, 0, 0);
          accB[fr][fc] = __builtin_amdgcn_mfma_f32_16x16x32_f16(af[kh][0][fr], bf[kh][1][fc], accB[fr][fc], 0, 0, 0);
          accB[fr][fc] = __builtin_amdgcn_mfma_f32_16x16x32_f16(af[kh][1][fr], bf[kh][0][fc], accB[fr][fc], 0, 0, 0);
        }
    __syncthreads();
  }

  #pragma unroll
  for (int fc = 0; fc < FC; ++fc) {
    const int n = bnk * BN + wc * WTN + fc * 16 + l16;
    const float eb = e1[n], sn = s1[n];
    #pragma unroll
    for (int fr = 0; fr < FR; ++fr) {
      const int row0 = bmk * BM + wr * WTM + fr * 16 + lq * 4;
      #pragma unroll
      for (int r = 0; r < 4; ++r) {
        const size_t idx = (size_t)(row0 + r) * N + n;
        float c = sn * (accA[fr][fc][r] + 0.000244140625f * accB[fr][fc][r]) + eb;
        float v = vst[idx], ii = ist[idx], z;
        lif_update(c, v, ii, z);
        vst[idx] = v; ist[idx] = ii;
        zout[idx] = (signed char)(z != 0.0f ? 1 : 0);
      }
    }
  }
}

// GEMM2/3: exact i8 spikes x 4 i8 digit planes (i32 accumulate) + fused LIF, z -> i8.
template<int BM, int BN>
__device__ __forceinline__ void gS_body(unsigned char* smem, int bnk, int bmk,
    const signed char* __restrict__ A, const signed char* __restrict__ Wq,
    const float* __restrict__ qs, const float* __restrict__ eb_,
    float* __restrict__ vst, float* __restrict__ ist,
    signed char* __restrict__ zout, const int N, const int K)
{
  constexpr int BKI = 128;
  constexpr int WTM = BM / 2, WTN = BN / 2, FR = WTM / 16, FC = WTN / 16;
  constexpr int RA = BM / 8, RB = BN / 8;
  typedef signed char (*I8A)[BKI];
  typedef signed char (*I8B)[BN][BKI];
  I8A As = (I8A)smem;                          // [BM][128]
  I8B Bs = (I8B)(smem + BM * BKI);             // [4][BN][128]
  const int tid = threadIdx.x, lane = tid & 63, wid = tid >> 6;
  const int wr = wid >> 1, wc = wid & 1;
  const int l16 = lane & 15, lq = lane >> 4;
  const size_t WPS = (size_t)N * K;
  const int lrow8 = lane >> 3, lslot = lane & 7;

  i32x4 acc[4][FR][FC] = {};

  auto stage = [&](int it) {
    const int k0 = it * BKI;
    #pragma unroll
    for (int q = 0; q < RA / 4; ++q) {
      int i = q * 4 + wid;
      int r0 = i * 8, row = r0 + lrow8;
      int ss = lslot ^ (row & 7);
      gl16(A + (size_t)(bmk * BM + row) * K + k0 + ss * 16, &As[r0][0]);
    }
    #pragma unroll
    for (int q = 0; q < RB; ++q) {
      int i = q * 4 + wid;
      int s = i / RB, r0 = (i % RB) * 8, row = r0 + lrow8;
      int ss = lslot ^ (row & 7);
      gl16(Wq + (size_t)s * WPS + (size_t)(bnk * BN + row) * K + k0 + ss * 16, &Bs[s][r0][0]);
    }
  };

  stage(0);
  __syncthreads();
  const int NK = K / BKI;
  for (int it = 0; it < NK; ++it) {
    i32x4 av[2][FR], bv[2][4][FC];
    #pragma unroll
    for (int kh = 0; kh < 2; ++kh) {
      #pragma unroll
      for (int fr = 0; fr < FR; ++fr) {
        int row = wr * WTM + fr * 16 + l16;
        int slot = ((kh << 2) | lq) ^ (row & 7);
        av[kh][fr] = *reinterpret_cast<const i32x4*>(&As[row][slot * 16]);
      }
      #pragma unroll
      for (int s = 0; s < 4; ++s)
        #pragma unroll
        for (int fc = 0; fc < FC; ++fc) {
          int row = wc * WTN + fc * 16 + l16;
          int slot = ((kh << 2) | lq) ^ (row & 7);
          bv[kh][s][fc] = *reinterpret_cast<const i32x4*>(&Bs[s][row][slot * 16]);
        }
    }
    __syncthreads();
    if (it + 1 < NK) stage(it + 1);
    #pragma unroll
    for (int kh = 0; kh < 2; ++kh)
      #pragma unroll
      for (int s = 0; s < 4; ++s)
        #pragma unroll
        for (int fr = 0; fr < FR; ++fr)
          #pragma unroll
          for (int fc = 0; fc < FC; ++fc)
            acc[s][fr][fc] = __builtin_amdgcn_mfma_i32_16x16x64_i8(av[kh][fr], bv[kh][s][fc], acc[s][fr][fc], 0, 0, 0);
    __syncthreads();
  }

  #pragma unroll
  for (int fc = 0; fc < FC; ++fc) {
    const int n = bnk * BN + wc * WTN + fc * 16 + l16;
    const float qv = qs[n], eb = eb_[n];
    #pragma unroll
    for (int fr = 0; fr < FR; ++fr) {
      const int row0 = bmk * BM + wr * WTM + fr * 16 + lq * 4;
      #pragma unroll
      for (int r = 0; r < 4; ++r) {
        const size_t idx = (size_t)(row0 + r) * N + n;
        int slo = acc[0][fr][fc][r] + (acc[1][fr][fc][r] << 7) + (acc[2][fr][fc][r] << 14);
        float c = qv * fmaf(2097152.0f, (float)acc[3][fr][fc][r], (float)slo) + eb;
        float v = vst[idx], ii = ist[idx], z;
        lif_update(c, v, ii, z);
        vst[idx] = v; ist[idx] = ii;
        zout[idx] = (signed char)(z != 0.0f ? 1 : 0);
      }
    }
  }
}

// Output layer: co = z3 @ Wout^T + bout, LIF, acc += z*wt  (z3 in i8)
__device__ __forceinline__ void out_body(int bid, const signed char* __restrict__ z3,
    const float* __restrict__ Wout, const float* __restrict__ bout,
    float* __restrict__ vo, float* __restrict__ io, float* __restrict__ acc, float wt)
{
  const int idx = bid * 256 + threadIdx.x;  // 0..4095
  if (idx >= BATCH * ODIM) return;
  const int b = idx >> 1, o = idx & 1;
  const signed char* zr = z3 + (size_t)b * H3;
  const float* wr = Wout + (size_t)o * H3;
  float s = 0.0f;
  for (int k0 = 0; k0 < H3; k0 += 16) {
    i32x4 zw = *reinterpret_cast<const i32x4*>(zr + k0);
    #pragma unroll
    for (int j = 0; j < 16; j++) {
      float zf = (float)((zw[j >> 2] >> ((j & 3) * 8)) & 1);
      s = fmaf(zf, wr[k0 + j], s);
    }
  }
  float cin = s + bout[o];
  float v = vo[idx], i = io[idx], z;
  lif_update(cin, v, i, z);
  vo[idx] = v; io[idx] = i;
  acc[idx] += z * wt;
}

// One dispatch per pipeline slot t: {G1(t), G2(t-1), G3(t-2), OUT(t-3)} — all independent.
__global__ __launch_bounds__(256, 2)
void fused_step(const _Float16* __restrict__ Xp, const _Float16* __restrict__ W1p,
                const float* __restrict__ s1, const float* __restrict__ e1,
                float* __restrict__ v1, float* __restrict__ i1, signed char* __restrict__ z1d,
                const signed char* __restrict__ W2q, const float* __restrict__ q2,
                const float* __restrict__ e2, float* __restrict__ v2, float* __restrict__ i2,
                signed char* __restrict__ z2d,
                const signed char* __restrict__ W3q, const float* __restrict__ q3,
                const float* __restrict__ e3, float* __restrict__ v3, float* __restrict__ i3,
                signed char* __restrict__ z3d,
                const float* __restrict__ Wout, const float* __restrict__ bout,
                float* __restrict__ vo, float* __restrict__ io, float* __restrict__ out,
                float wt, int t)
{
  __shared__ __align__(16) unsigned char smem[32768];
  const int r = blockIdx.x;
  if (r < 512) {                                   // G1(t): 64x64 tiles, (16 n, 32 m)
    if (t >= TDIM) return;
    g1_body(smem, r & 15, r >> 4,
            Xp + (size_t)t * BATCH * FDIM, W1p, s1, e1, v1, i1,
            z1d + (size_t)(t & 1) * BATCH * H1);
  } else if (r < 1024) {                           // G2(t-1): 64x32 tiles, (16 n, 32 m)
    const int tt = t - 1;
    if (tt < 0 || tt >= TDIM) return;
    const int r2 = r - 512;
    gS_body<64, 32>(smem, r2 & 15, r2 >> 4,
            z1d + (size_t)(tt & 1) * BATCH * H1, W2q, q2, e2, v2, i2,
            z2d + (size_t)(tt & 1) * BATCH * H2, H2, H1);
  } else if (r < 1536) {                           // G3(t-2): 32x32 tiles, (8 n, 64 m)
    const int tt = t - 2;
    if (tt < 0 || tt >= TDIM) return;
    const int r3 = r - 1024;
    gS_body<32, 32>(smem, r3 & 7, r3 >> 3,
            z2d + (size_t)(tt & 1) * BATCH * H2, W3q, q3, e3, v3, i3,
            z3d + (size_t)(tt & 1) * BATCH * H3, H3, H2);
  } else {                                         // OUT(t-3): 16 blocks
    const int tt = t - 3;
    if (tt < 0 || tt >= TDIM) return;
    out_body(r - 1536, z3d + (size_t)(tt & 1) * BATCH * H3, Wout, bout, vo, io, out, wt);
  }
}

// ---------------- fp32 fallback path (round-1 kernels) ----------------
__global__ void fold1_kernel(const float* __restrict__ W1, const float* __restrict__ b1,
                             const float* __restrict__ g1, const float* __restrict__ bb1,
                             const float* __restrict__ m1, const float* __restrict__ v1,
                             const float* __restrict__ gi, const float* __restrict__ bi,
                             const float* __restrict__ mi, const float* __restrict__ vi,
                             float* __restrict__ W1f, float* __restrict__ e1) {
  const int j = blockIdx.x;
  const int tid = threadIdx.x;
  const float sg = g1[j] / sqrtf(v1[j] + 1e-5f);
  float part = 0.0f;
  for (int f = tid; f < FDIM; f += 256) {
    float si = gi[f] / sqrtf(vi[f] + 1e-5f);
    float h0 = bi[f] - mi[f] * si;
    float w  = W1[j * FDIM + f];
    part += w * h0;
    W1f[j * FDIM + f] = w * si * sg;
  }
  #pragma unroll
  for (int m = 1; m < 64; m <<= 1) part += __shfl_xor(part, m);
  __shared__ float red[4];
  if ((tid & 63) == 0) red[tid >> 6] = part;
  __syncthreads();
  if (tid == 0) {
    float d = red[0] + red[1] + red[2] + red[3];
    e1[j] = (d + b1[j] - m1[j]) * sg + bb1[j];
  }
}

__global__ void foldS_kernel(const float* __restrict__ W, const float* __restrict__ b,
                             const float* __restrict__ g, const float* __restrict__ bb,
                             const float* __restrict__ m, const float* __restrict__ v,
                             float* __restrict__ Wf, float* __restrict__ e, int K) {
  const int j = blockIdx.x;
  const float sg = g[j] / sqrtf(v[j] + 1e-5f);
  for (int k = threadIdx.x; k < K; k += 256)
    Wf[j * K + k] = W[j * K + k] * sg;
  if (threadIdx.x == 0) e[j] = (b[j] - m[j]) * sg + bb[j];
}

template<int TM, int TN, bool CONTIG>
__global__ __launch_bounds__(256, 2)
void gemm_lif_kernel(const float* __restrict__ A, size_t ars, size_t acs,
                     const float* __restrict__ W, const float* __restrict__ ebias,
                     float* __restrict__ vst, float* __restrict__ ist,
                     float* __restrict__ zout, int N, int K)
{
  constexpr int BK = 16;
  constexpr int BM = 16 * TM;
  constexpr int BN = 16 * TN;
  __shared__ float As[BK][BM];
  __shared__ float Bs[BK][BN];
  const int tid = threadIdx.x;
  const int tx = tid & 15, ty = tid >> 4;
  const int bn = blockIdx.x, bm = blockIdx.y;
  const float* Ablk = A + (size_t)bm * BM * ars;
  const float* Wblk = W + (size_t)bn * BN * (size_t)K;

  float acc[TM][TN];
  #pragma unroll
  for (int r = 0; r < TM; r++)
    #pragma unroll
    for (int c = 0; c < TN; c++) acc[r][c] = 0.0f;

  for (int k0 = 0; k0 < K; k0 += BK) {
    if (CONTIG) {
      constexpr int A4 = BM * BK / 4;
      #pragma unroll
      for (int q = 0; q < A4 / 256; q++) {
        int idx = q * 256 + tid;
        int r = idx >> 2;
        int kq = (idx & 3) << 2;
        float4 val = *reinterpret_cast<const float4*>(Ablk + (size_t)r * ars + (size_t)(k0 + kq));
        As[kq + 0][r] = val.x; As[kq + 1][r] = val.y;
        As[kq + 2][r] = val.z; As[kq + 3][r] = val.w;
      }
    } else {
      #pragma unroll
      for (int q = 0; q < BM * BK / 256; q++) {
        int idx = q * 256 + tid;
        int r = idx >> 4;
        int kk = idx & 15;
        As[kk][r] = Ablk[(size_t)r * ars + (size_t)(k0 + kk) * acs];
      }
    }
    {
      int n  = tid >> 2;
      int kq = (tid & 3) << 2;
      float4 val = *reinterpret_cast<const float4*>(Wblk + (size_t)n * K + (size_t)(k0 + kq));
      Bs[kq + 0][n] = val.x; Bs[kq + 1][n] = val.y;
      Bs[kq + 2][n] = val.z; Bs[kq + 3][n] = val.w;
    }
    __syncthreads();
    #pragma unroll
    for (int kk = 0; kk < BK; kk++) {
      float a[TM], bv[TN];
      const float4* ap = reinterpret_cast<const float4*>(&As[kk][ty * TM]);
      *reinterpret_cast<float4*>(&a[0]) = ap[0];
      if (TM == 8) *reinterpret_cast<float4*>(&a[4]) = ap[1];
      *reinterpret_cast<float4*>(&bv[0]) = *reinterpret_cast<const float4*>(&Bs[kk][tx * TN]);
      #pragma unroll
      for (int r = 0; r < TM; r++)
        #pragma unroll
        for (int c = 0; c < TN; c++)
          acc[r][c] = fmaf(a[r], bv[c], acc[r][c]);
    }
    __syncthreads();
  }

  const int n0 = bn * BN + tx * TN;
  const float4 ev = *reinterpret_cast<const float4*>(ebias + n0);
  #pragma unroll
  for (int r = 0; r < TM; r++) {
    const int brow = bm * BM + ty * TM + r;
    const size_t idx = (size_t)brow * N + n0;
    float c0 = acc[r][0] + ev.x;
    float c1 = acc[r][1] + ev.y;
    float c2 = acc[r][2] + ev.z;
    float c3 = acc[r][3] + ev.w;
    float4 vv = *reinterpret_cast<const float4*>(vst + idx);
    float4 ii = *reinterpret_cast<const float4*>(ist + idx);
    float4 zz;
    lif_update(c0, vv.x, ii.x, zz.x);
    lif_update(c1, vv.y, ii.y, zz.y);
    lif_update(c2, vv.z, ii.z, zz.z);
    lif_update(c3, vv.w, ii.w, zz.w);
    *reinterpret_cast<float4*>(zout + idx) = zz;
    *reinterpret_cast<float4*>(vst  + idx) = vv;
    *reinterpret_cast<float4*>(ist  + idx) = ii;
  }
}

__global__ void out_kernel(const float* __restrict__ z3, const float* __restrict__ Wout,
                           const float* __restrict__ bout, float* __restrict__ vo,
                           float* __restrict__ io, float* __restrict__ acc, float wt) {
  const int idx = blockIdx.x * 256 + threadIdx.x;
  if (idx >= BATCH * ODIM) return;
  const int b = idx >> 1, o = idx & 1;
  const float4* zr = reinterpret_cast<const float4*>(z3 + (size_t)b * H3);
  const float4* wr = reinterpret_cast<const float4*>(Wout + o * H3);
  float s = 0.0f;
  #pragma unroll 4
  for (int k = 0; k < H3 / 4; k++) {
    float4 zv = zr[k], wv = wr[k];
    s += zv.x * wv.x + zv.y * wv.y + zv.z * wv.z + zv.w * wv.w;
  }
  float cin = s + bout[o];
  float v = vo[idx], i = io[idx], z;
  lif_update(cin, v, i, z);
  vo[idx] = v; io[idx] = i;
  acc[idx] += z * wt;
}

extern "C" void kernel_launch(void* const* d_in, const int* in_sizes, int n_in,
                              void* d_out, int out_size, void* d_ws, size_t ws_size,
                              hipStream_t stream) {
  const float* x     = (const float*)d_in[0];
  const float* bni_g = (const float*)d_in[1];
  const float* bni_b = (const float*)d_in[2];
  const float* bni_m = (const float*)d_in[3];
  const float* bni_v = (const float*)d_in[4];
  const float* W1    = (const float*)d_in[5];
  const float* b1    = (const float*)d_in[6];
  const float* bn1_g = (const float*)d_in[7];
  const float* bn1_b = (const float*)d_in[8];
  const float* bn1_m = (const float*)d_in[9];
  const float* bn1_v = (const float*)d_in[10];
  const float* W2    = (const float*)d_in[11];
  const float* b2    = (const float*)d_in[12];
  const float* bn2_g = (const float*)d_in[13];
  const float* bn2_b = (const float*)d_in[14];
  const float* bn2_m = (const float*)d_in[15];
  const float* bn2_v = (const float*)d_in[16];
  const float* W3    = (const float*)d_in[17];
  const float* b3    = (const float*)d_in[18];
  const float* bn3_g = (const float*)d_in[19];
  const float* bn3_b = (const float*)d_in[20];
  const float* bn3_m = (const float*)d_in[21];
  const float* bn3_v = (const float*)d_in[22];
  const float* Wout  = (const float*)d_in[23];
  const float* bout  = (const float*)d_in[24];
  float* out = (float*)d_out;

  float* ws = (float*)d_ws;
  size_t off = 0;
  auto alloc = [&](size_t n) { float* p = ws + off; off += n; return p; };

  // ---- MFMA path layout ----
  float* e1 = alloc(H1);
  float* e2 = alloc(H2);
  float* e3 = alloc(H3);
  float* s1 = alloc(H1);
  float* q2 = alloc(H2);
  float* q3 = alloc(H3);
  float* v1 = alloc((size_t)BATCH * H1);
  float* i1 = alloc((size_t)BATCH * H1);
  float* v2 = alloc((size_t)BATCH * H2);
  float* i2 = alloc((size_t)BATCH * H2);
  float* v3 = alloc((size_t)BATCH * H3);
  float* i3 = alloc((size_t)BATCH * H3);
  float* vo = alloc((size_t)BATCH * ODIM);
  float* io = alloc((size_t)BATCH * ODIM);
  _Float16* hs = (_Float16*)(ws + off);
  size_t hoff = 0;
  auto halloc = [&](size_t n) { _Float16* p = hs + hoff; hoff += n; return p; };
  _Float16* Xp  = halloc((size_t)2 * TDIM * BATCH * FDIM);
  _Float16* W1p = halloc((size_t)2 * H1 * FDIM);
  signed char* bs = (signed char*)(hs + hoff);
  size_t boff = 0;
  auto balloc = [&](size_t n) { signed char* p = bs + boff; boff += n; return p; };
  signed char* W2q = balloc((size_t)4 * H2 * H1);
  signed char* W3q = balloc((size_t)4 * H3 * H2);
  signed char* z1d = balloc((size_t)2 * BATCH * H1);
  signed char* z2d = balloc((size_t)2 * BATCH * H2);
  signed char* z3d = balloc((size_t)2 * BATCH * H3);
  const size_t mfma_needed = off * sizeof(float) + hoff * sizeof(_Float16) + boff;

  const int nstate = BATCH * (2 * H1 + 2 * H2 + 2 * H3 + 2 * ODIM);

  if (ws_size >= mfma_needed) {
    zero_kernel<<<2048, 256, 0, stream>>>(v1, nstate);
    zero_kernel<<<16, 256, 0, stream>>>(out, BATCH * ODIM);

    fold1_f16<<<H1, 256, 0, stream>>>(W1, b1, bn1_g, bn1_b, bn1_m, bn1_v,
                                      bni_g, bni_b, bni_m, bni_v, W1p, s1, e1);
    foldS_i8<<<H2, 256, 0, stream>>>(W2, b2, bn2_g, bn2_b, bn2_m, bn2_v, W2q, q2, e2, H2, H1);
    foldS_i8<<<H3, 256, 0, stream>>>(W3, b3, bn3_g, bn3_b, bn3_m, bn3_v, W3q, q3, e3, H3, H2);
    transpose_split_kernel<<<dim3(4, 16, 2048), 256, 0, stream>>>(x, Xp);

    for (int t = 0; t < TDIM + 3; t++) {
      float wt = (t >= 3) ? (float)std::pow(0.995, (double)(TDIM - 1 - (t - 3))) : 0.0f;
      fused_step<<<1552, 256, 0, stream>>>(Xp, W1p, s1, e1, v1, i1, z1d,
                                           W2q, q2, e2, v2, i2, z2d,
                                           W3q, q3, e3, v3, i3, z3d,
                                           Wout, bout, vo, io, out, wt, t);
    }
    return;
  }

  // ---- fp32 fallback (strided GEMM1, no transpose) ----
  off = 0;
  float* W1f = alloc((size_t)H1 * FDIM);
  float* W2f = alloc((size_t)H2 * H1);
  float* W3f = alloc((size_t)H3 * H2);
  float* fe1 = alloc(H1);
  float* fe2 = alloc(H2);
  float* fe3 = alloc(H3);
  float* fv1 = alloc((size_t)BATCH * H1);
  float* fi1 = alloc((size_t)BATCH * H1);
  float* fv2 = alloc((size_t)BATCH * H2);
  float* fi2 = alloc((size_t)BATCH * H2);
  float* fv3 = alloc((size_t)BATCH * H3);
  float* fi3 = alloc((size_t)BATCH * H3);
  float* fvo = alloc((size_t)BATCH * ODIM);
  float* fio = alloc((size_t)BATCH * ODIM);
  float* fz1 = alloc((size_t)BATCH * H1);
  float* fz2 = alloc((size_t)BATCH * H2);
  float* fz3 = alloc((size_t)BATCH * H3);

  zero_kernel<<<2048, 256, 0, stream>>>(fv1, nstate);
  zero_kernel<<<16, 256, 0, stream>>>(out, BATCH * ODIM);

  fold1_kernel<<<H1, 256, 0, stream>>>(W1, b1, bn1_g, bn1_b, bn1_m, bn1_v,
                                       bni_g, bni_b, bni_m, bni_v, W1f, fe1);
  foldS_kernel<<<H2, 256, 0, stream>>>(W2, b2, bn2_g, bn2_b, bn2_m, bn2_v, W2f, fe2, H1);
  foldS_kernel<<<H3, 256, 0, stream>>>(W3, b3, bn3_g, bn3_b, bn3_m, bn3_v, W3f, fe3, H2);

  const dim3 fg1(H1 / 64, BATCH / 128);
  const dim3 fg2(H2 / 64, BATCH / 64);
  const dim3 fg3(H3 / 64, BATCH / 64);

  for (int t = 0; t < TDIM; t++) {
    gemm_lif_kernel<8, 4, false><<<fg1, 256, 0, stream>>>(
        x + t, (size_t)FDIM * TDIM, TDIM, W1f, fe1, fv1, fi1, fz1, H1, FDIM);
    gemm_lif_kernel<4, 4, true><<<fg2, 256, 0, stream>>>(fz1, H1, 1, W2f, fe2, fv2, fi2, fz2, H2, H1);
    gemm_lif_kernel<4, 4, true><<<fg3, 256, 0, stream>>>(fz2, H2, 1, W3f, fe3, fv3, fi3, fz3, H3, H2);
    float wt = (float)std::pow(0.995, (double)(TDIM - 1 - t));
    out_kernel<<<BATCH * ODIM / 256, 256, 0, stream>>>(fz3, Wout, bout, fvo, fio, out, wt);
  }
}